// Round 11
// baseline (594.734 us; speedup 1.0000x reference)
//
#include <hip/hip_runtime.h>

#define LSEQ   4096
#define ROWS   16384             // 4 batches x 4096
#define EMBED  1024
#define NHEADS 16
#define HDIM   64
#define QKV_N  3072

typedef __attribute__((ext_vector_type(8))) short bf16x8;
typedef __attribute__((ext_vector_type(8))) unsigned short u16x8;
typedef __attribute__((ext_vector_type(4))) float f32x4;

// round-to-nearest-even fp32 -> bf16 (bit pattern), no header dependence
__device__ inline unsigned short bf16_rne(float x) {
    unsigned int u = __float_as_uint(x);
    unsigned int r = (u + 0x7fffu + ((u >> 16) & 1u)) >> 16;
    return (unsigned short)r;
}
__device__ inline float bf16_to_f32(unsigned short h) {
    return __uint_as_float(((unsigned int)h) << 16);
}

// swizzled short-index into a [64 rows][64 shorts] LDS tile (kv kernel)
__device__ __forceinline__ int swz64(int row, int s) {
    return row * 64 + ((((s >> 3) ^ (row & 7))) << 3) + (s & 7);
}

// ---------------------------------------------------------------------------
// Convert contiguous fp32 -> hi/lo bf16 arrays. n multiple of 1024.
// ---------------------------------------------------------------------------
__global__ __launch_bounds__(256)
void convert_hilo(const float* __restrict__ in, unsigned short* __restrict__ hi,
                  unsigned short* __restrict__ lo, int n)
{
    int i = (blockIdx.x * 256 + threadIdx.x) << 2;
    if (i >= n) return;
    float4 v = *reinterpret_cast<const float4*>(&in[i]);
    float a[4] = {v.x, v.y, v.z, v.w};
    unsigned short hh[4], ll[4];
    #pragma unroll
    for (int j = 0; j < 4; ++j) {
        hh[j] = bf16_rne(a[j]);
        ll[j] = bf16_rne(a[j] - bf16_to_f32(hh[j]));
    }
    *reinterpret_cast<ushort4*>(&hi[i]) = make_ushort4(hh[0], hh[1], hh[2], hh[3]);
    *reinterpret_cast<ushort4*>(&lo[i]) = make_ushort4(ll[0], ll[1], ll[2], ll[3]);
}

// ---------------------------------------------------------------------------
// Convert fp32 W[K][N] -> TRANSPOSED hi/lo bf16 Wt[N][K] (for B-operand).
// ---------------------------------------------------------------------------
__global__ __launch_bounds__(256)
void convert_T_hilo(const float* __restrict__ in, unsigned short* __restrict__ hi,
                    unsigned short* __restrict__ lo, int K, int N)
{
    __shared__ float tile[64][65];
    const int n0 = blockIdx.x * 64, k0 = blockIdx.y * 64;
    const int t = threadIdx.x;
    #pragma unroll
    for (int i = 0; i < 16; ++i) {
        int idx = t + i * 256;
        int r = idx >> 6, c = idx & 63;
        tile[r][c] = in[(size_t)(k0 + r) * N + n0 + c];
    }
    __syncthreads();
    #pragma unroll
    for (int i = 0; i < 16; ++i) {
        int idx = t + i * 256;
        int r = idx >> 6, c = idx & 63;
        float v = tile[c][r];
        unsigned short h = bf16_rne(v);
        unsigned short l = bf16_rne(v - bf16_to_f32(h));
        size_t o = (size_t)(n0 + r) * K + k0 + c;
        hi[o] = h;
        lo[o] = l;
    }
}

// ---------------------------------------------------------------------------
// bf16x3 split GEMM v8: C = A @ B^T_stored + bias (logical C = A @ B + bias)
// Reverts to R7(v4)'s MEASURED-ZERO-CONFLICT LDS geometry (three 32-row
// variants all measured 4.0 extra cy/read; v4 measured 0), scaled up:
// 128x128 block, 4 waves (2x2), each wave 64x64 = 4x4 frags of
// mfma_f32_16x16x32_bf16 (16 ds_read_b128 -> 48 executed MFMA / K-step).
// Tiles [128][32] shorts (Ah@0, Al@4096, Bh@8192, Bl@12288 per buffer);
// frag read off = r*32 + ((fq ^ ((r>>1)&3))<<3)  [byte-identical lane->bank
// map to R7]; staging source pre-swizzle (lane&3)^((lane>>3)&3), LDS-linear
// dest (m104/m173). Dbuf 1-ahead prefetch. LDS 64 KB -> 2 blocks/CU.
// M,N multiples of 128; K multiple of 32.
// C/D mapping (m89): col=lane&15, row=(lane>>4)*4+reg.
// ---------------------------------------------------------------------------
__global__ __launch_bounds__(256)
void gemm3_kernel(const unsigned short* __restrict__ Ah, const unsigned short* __restrict__ Al,
                  const unsigned short* __restrict__ Bh, const unsigned short* __restrict__ Bl,
                  const float* __restrict__ bias, float* __restrict__ C,
                  int K, int ldc)
{
    __shared__ __align__(16) unsigned short lds[2][16384];   // 64 KB

    const int t = threadIdx.x;
    const int wave = t >> 6, lane = t & 63;
    const int wr = wave >> 1, wc = wave & 1;     // wave tile: 64 rows x 64 cols
    const int rowBase = blockIdx.y * 128;
    const int colBase = blockIdx.x * 128;
    const int fr = lane & 15, fq = lane >> 4;

    // staging: wave w stages tile w (Ah/Al/Bh/Bl), 8 issues x 64 lanes x 16B
    const unsigned short* src = (wave == 0) ? Ah : (wave == 1) ? Al : (wave == 2) ? Bh : Bl;
    const int tileRow0 = (wave < 2) ? rowBase : colBase;
    const int ldsOff = wave * 4096;
    const int sRow = lane >> 2;                                  // 0..15
    const int sChunk = (((lane & 3) ^ ((lane >> 3) & 3)) << 3);  // swizzled k-chunk (elems)

    f32x4 acc[4][4] = {};
    const int NT = K >> 5;

    // prologue: stage tile 0 into buffer 0
    #pragma unroll
    for (int i = 0; i < 8; ++i) {
        const unsigned short* g = src + (size_t)(tileRow0 + i * 16 + sRow) * K + sChunk;
        __builtin_amdgcn_global_load_lds(
            (const __attribute__((address_space(1))) void*)g,
            (__attribute__((address_space(3))) void*)&lds[0][ldsOff + i * 512], 16, 0, 0);
    }
    __syncthreads();

    for (int tI = 0; tI < NT; ++tI) {
        const int cur = tI & 1;

        // prefetch next K-tile into the other buffer (in flight across MFMA)
        if (tI + 1 < NT) {
            const int k0 = (tI + 1) << 5;
            #pragma unroll
            for (int i = 0; i < 8; ++i) {
                const unsigned short* g =
                    src + (size_t)(tileRow0 + i * 16 + sRow) * K + k0 + sChunk;
                __builtin_amdgcn_global_load_lds(
                    (const __attribute__((address_space(1))) void*)g,
                    (__attribute__((address_space(3))) void*)&lds[cur ^ 1][ldsOff + i * 512], 16, 0, 0);
            }
        }

        // fragment reads (v4's zero-conflict pattern) + MFMA
        bf16x8 ah[4], al[4], bh[4], bl[4];
        #pragma unroll
        for (int m = 0; m < 4; ++m) {
            int r = wr * 64 + m * 16 + fr;
            int off = r * 32 + ((fq ^ ((r >> 1) & 3)) << 3);
            ah[m] = *reinterpret_cast<const bf16x8*>(&lds[cur][off]);
            al[m] = *reinterpret_cast<const bf16x8*>(&lds[cur][4096 + off]);
        }
        #pragma unroll
        for (int n = 0; n < 4; ++n) {
            int r = wc * 64 + n * 16 + fr;
            int off = r * 32 + ((fq ^ ((r >> 1) & 3)) << 3);
            bh[n] = *reinterpret_cast<const bf16x8*>(&lds[cur][8192 + off]);
            bl[n] = *reinterpret_cast<const bf16x8*>(&lds[cur][12288 + off]);
        }
        #pragma unroll
        for (int m = 0; m < 4; ++m)
            #pragma unroll
            for (int n = 0; n < 4; ++n) {
                acc[m][n] = __builtin_amdgcn_mfma_f32_16x16x32_bf16(ah[m], bh[n], acc[m][n], 0, 0, 0);
                acc[m][n] = __builtin_amdgcn_mfma_f32_16x16x32_bf16(ah[m], bl[n], acc[m][n], 0, 0, 0);
                acc[m][n] = __builtin_amdgcn_mfma_f32_16x16x32_bf16(al[m], bh[n], acc[m][n], 0, 0, 0);
            }

        __syncthreads();  // drains this iter's prefetch (overlapped with MFMA above)
    }

    // epilogue: C/D frag mapping col=lane&15, row=(lane>>4)*4+reg (m89-verified)
    #pragma unroll
    for (int m = 0; m < 4; ++m) {
        #pragma unroll
        for (int n = 0; n < 4; ++n) {
            int col = colBase + wc * 64 + n * 16 + fr;
            float bv = bias[col];
            #pragma unroll
            for (int r = 0; r < 4; ++r) {
                int row = rowBase + wr * 64 + m * 16 + fq * 4 + r;
                C[(size_t)row * ldc + col] = acc[m][n][r] + bv;
            }
        }
    }
}

// ---------------------------------------------------------------------------
// kv MFMA kernel, full-batch (unchanged): per (256-row chunk, head).
// ---------------------------------------------------------------------------
__global__ __launch_bounds__(256)
void kv_mfma_kernel(const float* __restrict__ kvb, const float* __restrict__ cosb,
                    const float* __restrict__ sinb, const float* __restrict__ maskb,
                    const float* __restrict__ proj, float* __restrict__ partial)
{
    __shared__ __align__(16) char smem[66816];
    unsigned short* KR_h  = (unsigned short*)smem;
    unsigned short* KR_l  = (unsigned short*)(smem + 8192);
    float*          PS    = (float*)smem;                    // aliases KR (fp32 [64][64])
    unsigned short* PJT_h = (unsigned short*)(smem + 16384);
    unsigned short* PJT_l = (unsigned short*)(smem + 24576);
    unsigned short* KPT_h = (unsigned short*)(smem + 32768);
    unsigned short* KPT_l = (unsigned short*)(smem + 40960);
    unsigned short* VT_h  = (unsigned short*)(smem + 49152);
    unsigned short* VT_l  = (unsigned short*)(smem + 57344);
    float*          MS    = (float*)(smem + 65536);
    float*          KS    = (float*)(smem + 65792);

    const int chunk = blockIdx.x;   // 0..63 (256 rows each)
    const int hh    = blockIdx.y;   // 0..15
    const int t = threadIdx.x;
    const int w = t >> 6, lane = t & 63;
    const int fr = lane & 15, fq = lane >> 4;

    {
        int r = t >> 2, c0 = (t & 3) << 4;
        #pragma unroll
        for (int k = 0; k < 4; ++k)
            *reinterpret_cast<float4*>(&PS[r * 64 + c0 + k * 4]) =
                *reinterpret_cast<const float4*>(&proj[(size_t)hh * 4096 + r * 64 + c0 + k * 4]);
    }
    __syncthreads();
    {
        int m = t >> 2, d0 = (t & 3) << 4;
        unsigned short hb[16], lb[16];
        #pragma unroll
        for (int j = 0; j < 16; ++j) {
            float v = PS[(d0 + j) * 64 + m];
            hb[j] = bf16_rne(v);
            lb[j] = bf16_rne(v - bf16_to_f32(hb[j]));
        }
        #pragma unroll
        for (int cp = 0; cp < 2; ++cp) {
            u16x8 vh, vl;
            #pragma unroll
            for (int j = 0; j < 8; ++j) { vh[j] = hb[cp * 8 + j]; vl[j] = lb[cp * 8 + j]; }
            int sidx = swz64(m, d0 + cp * 8);
            *reinterpret_cast<u16x8*>(&PJT_h[sidx]) = vh;
            *reinterpret_cast<u16x8*>(&PJT_l[sidx]) = vl;
        }
    }
    __syncthreads();

    f32x4 acc2[4] = {};
    float ksacc[4] = {0.f, 0.f, 0.f, 0.f};

    for (int sub = 0; sub < 4; ++sub) {
        const int rowL = chunk * 256 + sub * 64;   // global row

        float4 vv[4];
        {
            int l = t >> 2, c0 = (t & 3) << 4;
            #pragma unroll
            for (int k2 = 0; k2 < 4; ++k2)
                vv[k2] = *reinterpret_cast<const float4*>(
                    &kvb[(size_t)(rowL + l) * 2048 + 1024 + hh * 64 + c0 + k2 * 4]);
        }
        #pragma unroll
        for (int i = 0; i < 8; ++i) {
            int p = t + (i << 8);
            int l = p >> 5, i2 = p & 31;
            size_t base = (size_t)(rowL + l) * 2048 + hh * 64 + 2 * i2;
            float kr = kvb[base], ki = kvb[base + 1];
            int crow = (rowL + l) & 4095;
            float c = cosb[(size_t)crow * 32 + i2];
            float s = sinb[(size_t)crow * 32 + i2];
            float xr = kr * c - ki * s;
            float xi = kr * s + ki * c;
            unsigned short h0 = bf16_rne(xr), h1 = bf16_rne(xi);
            unsigned short l0 = bf16_rne(xr - bf16_to_f32(h0));
            unsigned short l1 = bf16_rne(xi - bf16_to_f32(h1));
            int sidx = swz64(l, 2 * i2);
            *reinterpret_cast<unsigned int*>(&KR_h[sidx]) = (unsigned)h0 | ((unsigned)h1 << 16);
            *reinterpret_cast<unsigned int*>(&KR_l[sidx]) = (unsigned)l0 | ((unsigned)l1 << 16);
        }
        if (t < 64) MS[t] = maskb[rowL + t];
        __syncthreads();   // B1

        f32x4 acc1[4] = {};
        #pragma unroll
        for (int ks = 0; ks < 2; ++ks) {
            bf16x8 ah = *reinterpret_cast<const bf16x8*>(&KR_h[swz64(16 * w + fr, ks * 32 + fq * 8)]);
            bf16x8 al = *reinterpret_cast<const bf16x8*>(&KR_l[swz64(16 * w + fr, ks * 32 + fq * 8)]);
            #pragma unroll
            for (int n = 0; n < 4; ++n) {
                bf16x8 bh = *reinterpret_cast<const bf16x8*>(&PJT_h[swz64(16 * n + fr, ks * 32 + fq * 8)]);
                bf16x8 bl = *reinterpret_cast<const bf16x8*>(&PJT_l[swz64(16 * n + fr, ks * 32 + fq * 8)]);
                acc1[n] = __builtin_amdgcn_mfma_f32_16x16x32_bf16(ah, bh, acc1[n], 0, 0, 0);
                acc1[n] = __builtin_amdgcn_mfma_f32_16x16x32_bf16(ah, bl, acc1[n], 0, 0, 0);
                acc1[n] = __builtin_amdgcn_mfma_f32_16x16x32_bf16(al, bh, acc1[n], 0, 0, 0);
            }
        }
        #pragma unroll
        for (int n = 0; n < 4; ++n) {
            unsigned short hb[4], lb[4];
            float ssum = 0.f;
            #pragma unroll
            for (int r = 0; r < 4; ++r) {
                int l = 16 * w + fq * 4 + r;
                float kp = fmaxf(acc1[n][r], 0.f) * MS[l];
                ssum += kp;
                hb[r] = bf16_rne(kp);
                lb[r] = bf16_rne(kp - bf16_to_f32(hb[r]));
            }
            ksacc[n] += ssum;
            int sidx = swz64(16 * n + fr, 16 * w + fq * 4);
            *reinterpret_cast<ushort4*>(&KPT_h[sidx]) = make_ushort4(hb[0], hb[1], hb[2], hb[3]);
            *reinterpret_cast<ushort4*>(&KPT_l[sidx]) = make_ushort4(lb[0], lb[1], lb[2], lb[3]);
        }
        __syncthreads();   // B2

        {
            float* VS = PS;
            int l = t >> 2, c0 = (t & 3) << 4;
            float mv = MS[l];
            #pragma unroll
            for (int k2 = 0; k2 < 4; ++k2) {
                float4 q = vv[k2];
                q.x *= mv; q.y *= mv; q.z *= mv; q.w *= mv;
                *reinterpret_cast<float4*>(&VS[l * 64 + c0 + k2 * 4]) = q;
            }
        }
        __syncthreads();   // B3

        {
            float* VS = PS;
            int d = t >> 2, l0 = (t & 3) << 4;
            unsigned short hb[16], lb[16];
            #pragma unroll
            for (int j = 0; j < 16; ++j) {
                float v = VS[(l0 + j) * 64 + d];
                hb[j] = bf16_rne(v);
                lb[j] = bf16_rne(v - bf16_to_f32(hb[j]));
            }
            #pragma unroll
            for (int cp = 0; cp < 2; ++cp) {
                u16x8 vh, vl;
                #pragma unroll
                for (int j = 0; j < 8; ++j) { vh[j] = hb[cp * 8 + j]; vl[j] = lb[cp * 8 + j]; }
                int sidx = swz64(d, l0 + cp * 8);
                *reinterpret_cast<u16x8*>(&VT_h[sidx]) = vh;
                *reinterpret_cast<u16x8*>(&VT_l[sidx]) = vl;
            }
        }
        __syncthreads();   // B4

        #pragma unroll
        for (int ks = 0; ks < 2; ++ks) {
            bf16x8 ah = *reinterpret_cast<const bf16x8*>(&KPT_h[swz64(16 * w + fr, ks * 32 + fq * 8)]);
            bf16x8 al = *reinterpret_cast<const bf16x8*>(&KPT_l[swz64(16 * w + fr, ks * 32 + fq * 8)]);
            #pragma unroll
            for (int n = 0; n < 4; ++n) {
                bf16x8 bh = *reinterpret_cast<const bf16x8*>(&VT_h[swz64(16 * n + fr, ks * 32 + fq * 8)]);
                bf16x8 bl = *reinterpret_cast<const bf16x8*>(&VT_l[swz64(16 * n + fr, ks * 32 + fq * 8)]);
                acc2[n] = __builtin_amdgcn_mfma_f32_16x16x32_bf16(ah, bh, acc2[n], 0, 0, 0);
                acc2[n] = __builtin_amdgcn_mfma_f32_16x16x32_bf16(ah, bl, acc2[n], 0, 0, 0);
                acc2[n] = __builtin_amdgcn_mfma_f32_16x16x32_bf16(al, bh, acc2[n], 0, 0, 0);
            }
        }
    }

    #pragma unroll
    for (int n = 0; n < 4; ++n) {
        float v = ksacc[n];
        v += __shfl_xor(v, 16);
        v += __shfl_xor(v, 32);
        if (fq == 0) KS[w * 64 + 16 * n + fr] = v;
    }
    __syncthreads();

    float* dst = partial + ((size_t)hh * 64 + chunk) * 4160;
    #pragma unroll
    for (int n = 0; n < 4; ++n)
        #pragma unroll
        for (int r = 0; r < 4; ++r) {
            int m = 16 * w + fq * 4 + r;
            int d = 16 * n + fr;
            dst[m * 64 + d] = acc2[n][r];
        }
    if (t < 64)
        dst[4096 + t] = KS[t] + KS[64 + t] + KS[128 + t] + KS[192 + t];
}

// Reduce 16 per-batch chunk partials -> kv (64x64) + ksum (64) per (b,h).
__global__ __launch_bounds__(256)
void kv_reduce_kernel(const float* __restrict__ partial, float* __restrict__ kvout)
{
    const int bh = blockIdx.x;          // b*16 + h
    const int b = bh >> 4, h = bh & 15;
    const int seg = blockIdx.y;         // 4160 = 4 segments x 1040
    for (int idx = seg * 1040 + threadIdx.x; idx < (seg + 1) * 1040; idx += 256) {
        float s = 0.f;
        for (int c = 0; c < 16; ++c)
            s += partial[((size_t)h * 64 + b * 16 + c) * 4160 + idx];
        kvout[(size_t)bh * 4160 + idx] = s;
    }
}

// ---------------------------------------------------------------------------
// context, full-batch (unchanged): grid (256, 16).
// ---------------------------------------------------------------------------
__global__ __launch_bounds__(256)
void context_kernel(const float* __restrict__ qb, const float* __restrict__ cosb,
                    const float* __restrict__ sinb, const float* __restrict__ proj,
                    const float* __restrict__ kvsum, unsigned short* __restrict__ ch,
                    unsigned short* __restrict__ cl)
{
    const int lt = blockIdx.x;   // 0..255
    const int h  = blockIdx.y;   // 0..15
    const int t = threadIdx.x;
    const int bh = (lt >> 6) * 16 + h;

    __shared__ float bufA[64][68];
    __shared__ float qp[64][68];
    __shared__ float pj[64][64];
    __shared__ float ksum[64];

    for (int i = t; i < 1024; i += 256)
        *reinterpret_cast<float4*>(&pj[0][0] + (size_t)i * 4) =
            *reinterpret_cast<const float4*>(proj + (size_t)h * 4096 + (size_t)i * 4);
    if (t < 64) ksum[t] = kvsum[(size_t)bh * 4160 + 4096 + t];

    const int rowL = lt * 64;            // global row
    #pragma unroll
    for (int i = 0; i < 8; ++i) {
        int p = t + i * 256;
        int l = p >> 5, i2 = p & 31;
        size_t base = (size_t)(rowL + l) * 1024 + h * HDIM + 2 * i2;
        float qr = qb[base], qi = qb[base + 1];
        int crow = (rowL + l) & 4095;
        float c = cosb[(size_t)crow * 32 + i2];
        float s = sinb[(size_t)crow * 32 + i2];
        bufA[l][2 * i2]     = qr * c - qi * s;
        bufA[l][2 * i2 + 1] = qr * s + qi * c;
    }
    __syncthreads();

    {
        int l = t >> 2, m0 = (t & 3) << 4;
        float a[16] = {};
        for (int d = 0; d < 64; ++d) {
            float ql = bufA[l][d];
            const float* pr = &pj[d][m0];
            #pragma unroll
            for (int j = 0; j < 16; ++j) a[j] = fmaf(ql, pr[j], a[j]);
        }
        #pragma unroll
        for (int j = 0; j < 16; ++j) qp[l][m0 + j] = fmaxf(a[j], 0.f);
    }
    __syncthreads();

    #pragma unroll
    for (int i = 0; i < 4; ++i) {
        int idx = t + i * 256;
        int mm = idx >> 4, dd = (idx & 15) << 2;
        *reinterpret_cast<float4*>(&bufA[mm][dd]) =
            *reinterpret_cast<const float4*>(&kvsum[(size_t)bh * 4160 + mm * 64 + dd]);
    }
    __syncthreads();

    {
        int l = t >> 2, d0 = (t & 3) << 4;
        float a[16] = {};
        float nrm = 0.f;
        for (int mm = 0; mm < 64; ++mm) {
            float qv = qp[l][mm];
            nrm = fmaf(qv, ksum[mm], nrm);
            const float* kr = &bufA[mm][d0];
            #pragma unroll
            for (int j = 0; j < 16; ++j) a[j] = fmaf(qv, kr[j], a[j]);
        }
        float inv = 1.0f / (nrm + 1e-4f);
        size_t orow = (size_t)(rowL + l) * 1024 + h * HDIM + d0;
        #pragma unroll
        for (int j4 = 0; j4 < 4; ++j4) {
            unsigned short hh2[4], ll2[4];
            #pragma unroll
            for (int j = 0; j < 4; ++j) {
                float v = a[j4 * 4 + j] * inv;
                hh2[j] = bf16_rne(v);
                ll2[j] = bf16_rne(v - bf16_to_f32(hh2[j]));
            }
            *reinterpret_cast<ushort4*>(&ch[orow + j4 * 4]) = make_ushort4(hh2[0], hh2[1], hh2[2], hh2[3]);
            *reinterpret_cast<ushort4*>(&cl[orow + j4 * 4]) = make_ushort4(ll2[0], ll2[1], ll2[2], ll2[3]);
        }
    }
}

extern "C" void kernel_launch(void* const* d_in, const int* in_sizes, int n_in,
                              void* d_out, int out_size, void* d_ws, size_t ws_size,
                              hipStream_t stream)
{
    const float* x    = (const float*)d_in[0];
    const float* fcos = (const float*)d_in[1];
    const float* fsin = (const float*)d_in[2];
    const float* mask = (const float*)d_in[3];
    const float* Wqkv = (const float*)d_in[4];
    const float* bqkv = (const float*)d_in[5];
    const float* proj = (const float*)d_in[6];
    const float* Wout = (const float*)d_in[7];
    const float* bout = (const float*)d_in[8];
    float* out = (float*)d_out;

    // Workspace (floats), 59,052,032 fl = 236.2 MB (< 256 MiB ws).
    float* W    = (float*)d_ws;          //  4,194,304 fl: weights hi/lo (transposed)
    float* XHL  = W + 4194304;           // 16,777,216 fl: x hi+lo bf16 -> later ctx hi+lo
    float* KVQ  = XHL + 16777216;        // 33,554,432 fl: KV fp32 [16384][2048] -> later Q [16384][1024]
    float* PART = KVQ + 33554432;        //  4,259,840 fl: partials [16][64][4160]
    float* KSUM = PART + 4259840;        //    266,240 fl: kvsum [64][4160]

    unsigned short* Wqh = (unsigned short*)W;       // Wqkv^T hi: [3072][1024]
    unsigned short* Wql = Wqh + 3145728;
    unsigned short* Woh = Wql + 3145728;            // Wout^T hi: [1024][1024]
    unsigned short* Wol = Woh + 1048576;
    unsigned short* xh  = (unsigned short*)XHL;     // also ctx hi (x dead by then)
    unsigned short* xl  = xh + 16777216;            // also ctx lo

    // Weight conversions (once per launch), transposed for B-operand K-contiguity
    convert_T_hilo<<<dim3(3072 / 64, 1024 / 64), 256, 0, stream>>>(Wqkv, Wqh, Wql, 1024, 3072);
    convert_T_hilo<<<dim3(1024 / 64, 1024 / 64), 256, 0, stream>>>(Wout, Woh, Wol, 1024, 1024);

    // x -> hi/lo, full batch
    convert_hilo<<<16384, 256, 0, stream>>>(x, xh, xl, ROWS * EMBED);

    // K,V = x @ Wqkv[:,1024:3072] + bqkv[1024:]  (full batch, [16384][2048])
    gemm3_kernel<<<dim3(2048 / 128, ROWS / 128), 256, 0, stream>>>(
        xh, xl, Wqh + (size_t)1024 * 1024, Wql + (size_t)1024 * 1024,
        bqkv + 1024, KVQ, 1024, 2048);

    // fused RoPE+proj+relu+mask -> kv partials (full batch)
    kv_mfma_kernel<<<dim3(64, 16), 256, 0, stream>>>(KVQ, fcos, fsin, mask, proj, PART);

    // reduce partials -> kv/ksum per (b,h)
    kv_reduce_kernel<<<dim3(64, 4), 256, 0, stream>>>(PART, KSUM);

    // Q = x @ Wqkv[:,0:1024] + bqkv[0:1024]  (overwrites KV region; KV dead)
    gemm3_kernel<<<dim3(1024 / 128, ROWS / 128), 256, 0, stream>>>(
        xh, xl, Wqh, Wql, bqkv, KVQ, 1024, 1024);

    // context + normalization; writes ctx hi/lo over xh/xl (x dead)
    context_kernel<<<dim3(256, 16), 256, 0, stream>>>(
        KVQ, fcos, fsin, proj, KSUM, xh, xl);

    // out = ctx @ Wout + bout
    gemm3_kernel<<<dim3(1024 / 128, ROWS / 128), 256, 0, stream>>>(
        xh, xl, Woh, Wol, bout, out, 1024, 1024);
}

// Round 12
// 517.290 us; speedup vs baseline: 1.1497x; 1.1497x over previous
//
#include <hip/hip_runtime.h>

#define LSEQ   4096
#define ROWS   16384             // 4 batches x 4096
#define EMBED  1024
#define NHEADS 16
#define HDIM   64
#define QKV_N  3072

typedef __attribute__((ext_vector_type(8))) short bf16x8;
typedef __attribute__((ext_vector_type(8))) unsigned short u16x8;
typedef __attribute__((ext_vector_type(4))) float f32x4;

// round-to-nearest-even fp32 -> bf16 (bit pattern), no header dependence
__device__ inline unsigned short bf16_rne(float x) {
    unsigned int u = __float_as_uint(x);
    unsigned int r = (u + 0x7fffu + ((u >> 16) & 1u)) >> 16;
    return (unsigned short)r;
}
__device__ inline float bf16_to_f32(unsigned short h) {
    return __uint_as_float(((unsigned int)h) << 16);
}

// swizzled short-index into a [64 rows][64 shorts] LDS tile (kv kernel)
__device__ __forceinline__ int swz64(int row, int s) {
    return row * 64 + ((((s >> 3) ^ (row & 7))) << 3) + (s & 7);
}

// ---------------------------------------------------------------------------
// Convert contiguous fp32 -> hi/lo bf16 arrays. n multiple of 1024.
// ---------------------------------------------------------------------------
__global__ __launch_bounds__(256)
void convert_hilo(const float* __restrict__ in, unsigned short* __restrict__ hi,
                  unsigned short* __restrict__ lo, int n)
{
    int i = (blockIdx.x * 256 + threadIdx.x) << 2;
    if (i >= n) return;
    float4 v = *reinterpret_cast<const float4*>(&in[i]);
    float a[4] = {v.x, v.y, v.z, v.w};
    unsigned short hh[4], ll[4];
    #pragma unroll
    for (int j = 0; j < 4; ++j) {
        hh[j] = bf16_rne(a[j]);
        ll[j] = bf16_rne(a[j] - bf16_to_f32(hh[j]));
    }
    *reinterpret_cast<ushort4*>(&hi[i]) = make_ushort4(hh[0], hh[1], hh[2], hh[3]);
    *reinterpret_cast<ushort4*>(&lo[i]) = make_ushort4(ll[0], ll[1], ll[2], ll[3]);
}

// ---------------------------------------------------------------------------
// Convert fp32 W[K][N] -> TRANSPOSED hi/lo bf16 Wt[N][K] (for B-operand).
// ---------------------------------------------------------------------------
__global__ __launch_bounds__(256)
void convert_T_hilo(const float* __restrict__ in, unsigned short* __restrict__ hi,
                    unsigned short* __restrict__ lo, int K, int N)
{
    __shared__ float tile[64][65];
    const int n0 = blockIdx.x * 64, k0 = blockIdx.y * 64;
    const int t = threadIdx.x;
    #pragma unroll
    for (int i = 0; i < 16; ++i) {
        int idx = t + i * 256;
        int r = idx >> 6, c = idx & 63;
        tile[r][c] = in[(size_t)(k0 + r) * N + n0 + c];
    }
    __syncthreads();
    #pragma unroll
    for (int i = 0; i < 16; ++i) {
        int idx = t + i * 256;
        int r = idx >> 6, c = idx & 63;
        float v = tile[c][r];
        unsigned short h = bf16_rne(v);
        unsigned short l = bf16_rne(v - bf16_to_f32(h));
        size_t o = (size_t)(n0 + r) * K + k0 + c;
        hi[o] = h;
        lo[o] = l;
    }
}

// ---------------------------------------------------------------------------
// bf16x3 split GEMM v9: 8-phase 256x256 port (learn_hip m201 template).
// C = A @ B^T_stored + bias. 8 waves (2M x 4N), 512 thr, per-wave 128x64 =
// 8x4 frags of mfma_f32_16x16x32_bf16, BK=32, x3 products = 96 MFMA/wave/tile.
// LDS 128 KB: 2 dbuf x {Ah,Al,Bh,Bl}[256][32] shorts, v8's measured-zero-
// conflict swizzle (staging src chunk (lane&3)^((lane>>3)&3); frag read
// off = r*32 + ((fq^((r>>1)&3))<<3)).
// 4 phases per K-tile: {issue 3/3/2/0 prefetch gload_lds || ds_read 4 A-frags
// (+8 B-frags in p0, reg-resident) -> RAW s_barrier (loads stay in flight) ->
// lgkmcnt(0)+sched_barrier -> setprio(1)+24 MFMA+setprio(0) -> barrier}.
// Single vmcnt(0) per K-tile at p3, >=2 phases after last issue (pre-satisfied).
// M,N multiples of 256; K multiple of 32.
// ---------------------------------------------------------------------------
__global__ __launch_bounds__(512)
void gemm3_kernel(const unsigned short* __restrict__ Ah, const unsigned short* __restrict__ Al,
                  const unsigned short* __restrict__ Bh, const unsigned short* __restrict__ Bl,
                  const float* __restrict__ bias, float* __restrict__ C,
                  int K, int ldc)
{
    __shared__ __align__(16) unsigned short lds[2][32768];   // 128 KB

    const int t = threadIdx.x;
    const int wave = t >> 6, lane = t & 63;
    const int wr = wave >> 2, wc = wave & 3;     // wave tile: 128 rows x 64 cols
    const int rowBase = blockIdx.y * 256;
    const int colBase = blockIdx.x * 256;
    const int fr = lane & 15, fq = lane >> 4;

    // staging: waves 0-1 Ah, 2-3 Al, 4-5 Bh, 6-7 Bl; each wave a 128-row half.
    const int op = wave >> 1;
    const unsigned short* src = (op == 0) ? Ah : (op == 1) ? Al : (op == 2) ? Bh : Bl;
    const int tileRow0 = ((wave < 4) ? rowBase : colBase) + (wave & 1) * 128;
    const int subOff = op * 8192 + (wave & 1) * 4096;            // shorts
    const int sRow = lane >> 2;                                  // 0..15
    const int sChunk = (((lane & 3) ^ ((lane >> 3) & 3)) << 3);  // swizzled k-chunk

    f32x4 acc[8][4] = {};
    const int NT = K >> 5;

    // prologue: stage tile 0 into buffer 0 (full drain once via __syncthreads)
    #pragma unroll
    for (int i = 0; i < 8; ++i) {
        const unsigned short* g = src + (size_t)(tileRow0 + i * 16 + sRow) * K + sChunk;
        __builtin_amdgcn_global_load_lds(
            (const __attribute__((address_space(1))) void*)g,
            (__attribute__((address_space(3))) void*)&lds[0][subOff + i * 512], 16, 0, 0);
    }
    __syncthreads();

    for (int tI = 0; tI < NT; ++tI) {
        const int cur = tI & 1;
        const unsigned short* ldsC = lds[cur];
        const int k0 = (tI + 1) << 5;
        const bool pref = (tI + 1 < NT);

        bf16x8 bhf[4], blf[4];   // B fragments, register-resident across phases

        #pragma unroll
        for (int p = 0; p < 4; ++p) {
            // issue prefetch portion for tile t+1 (3,3,2,0) into other buffer
            if (pref) {
                const int i0 = (p == 0) ? 0 : (p == 1) ? 3 : (p == 2) ? 6 : 8;
                const int i1 = (p == 0) ? 3 : (p == 1) ? 6 : (p == 2) ? 8 : 8;
                for (int i = i0; i < i1; ++i) {
                    const unsigned short* g =
                        src + (size_t)(tileRow0 + i * 16 + sRow) * K + k0 + sChunk;
                    __builtin_amdgcn_global_load_lds(
                        (const __attribute__((address_space(1))) void*)g,
                        (__attribute__((address_space(3))) void*)&lds[cur ^ 1][subOff + i * 512], 16, 0, 0);
                }
            }

            // ds_read this phase's A-frags (and all B-frags in phase 0)
            bf16x8 ahf[2], alf[2];
            #pragma unroll
            for (int mm = 0; mm < 2; ++mm) {
                int m = p * 2 + mm;
                int r = wr * 128 + m * 16 + fr;
                int off = r * 32 + ((fq ^ ((r >> 1) & 3)) << 3);
                ahf[mm] = *reinterpret_cast<const bf16x8*>(&ldsC[off]);
                alf[mm] = *reinterpret_cast<const bf16x8*>(&ldsC[8192 + off]);
            }
            if (p == 0) {
                #pragma unroll
                for (int n = 0; n < 4; ++n) {
                    int rb = wc * 64 + n * 16 + fr;
                    int off = rb * 32 + ((fq ^ ((rb >> 1) & 3)) << 3);
                    bhf[n] = *reinterpret_cast<const bf16x8*>(&ldsC[16384 + off]);
                    blf[n] = *reinterpret_cast<const bf16x8*>(&ldsC[24576 + off]);
                }
            }

            __builtin_amdgcn_s_barrier();                       // raw: no vm drain
            asm volatile("s_waitcnt lgkmcnt(0)" ::: "memory");
            __builtin_amdgcn_sched_barrier(0);                  // rule #18 fence
            __builtin_amdgcn_s_setprio(1);
            #pragma unroll
            for (int mm = 0; mm < 2; ++mm) {
                int m = p * 2 + mm;
                #pragma unroll
                for (int n = 0; n < 4; ++n) {
                    acc[m][n] = __builtin_amdgcn_mfma_f32_16x16x32_bf16(ahf[mm], bhf[n], acc[m][n], 0, 0, 0);
                    acc[m][n] = __builtin_amdgcn_mfma_f32_16x16x32_bf16(ahf[mm], blf[n], acc[m][n], 0, 0, 0);
                    acc[m][n] = __builtin_amdgcn_mfma_f32_16x16x32_bf16(alf[mm], bhf[n], acc[m][n], 0, 0, 0);
                }
            }
            __builtin_amdgcn_s_setprio(0);
            if (p == 3)  // tile t+1 fully staged? last issues were 2 phases ago
                asm volatile("s_waitcnt vmcnt(0)" ::: "memory");
            __builtin_amdgcn_s_barrier();
        }
    }

    // epilogue: C/D frag mapping col=lane&15, row=(lane>>4)*4+reg (m89-verified)
    #pragma unroll
    for (int m = 0; m < 8; ++m) {
        #pragma unroll
        for (int n = 0; n < 4; ++n) {
            int col = colBase + wc * 64 + n * 16 + fr;
            float bv = bias[col];
            #pragma unroll
            for (int r = 0; r < 4; ++r) {
                int row = rowBase + wr * 128 + m * 16 + fq * 4 + r;
                C[(size_t)row * ldc + col] = acc[m][n][r] + bv;
            }
        }
    }
}

// ---------------------------------------------------------------------------
// kv MFMA kernel, full-batch (unchanged): per (256-row chunk, head).
// ---------------------------------------------------------------------------
__global__ __launch_bounds__(256)
void kv_mfma_kernel(const float* __restrict__ kvb, const float* __restrict__ cosb,
                    const float* __restrict__ sinb, const float* __restrict__ maskb,
                    const float* __restrict__ proj, float* __restrict__ partial)
{
    __shared__ __align__(16) char smem[66816];
    unsigned short* KR_h  = (unsigned short*)smem;
    unsigned short* KR_l  = (unsigned short*)(smem + 8192);
    float*          PS    = (float*)smem;                    // aliases KR (fp32 [64][64])
    unsigned short* PJT_h = (unsigned short*)(smem + 16384);
    unsigned short* PJT_l = (unsigned short*)(smem + 24576);
    unsigned short* KPT_h = (unsigned short*)(smem + 32768);
    unsigned short* KPT_l = (unsigned short*)(smem + 40960);
    unsigned short* VT_h  = (unsigned short*)(smem + 49152);
    unsigned short* VT_l  = (unsigned short*)(smem + 57344);
    float*          MS    = (float*)(smem + 65536);
    float*          KS    = (float*)(smem + 65792);

    const int chunk = blockIdx.x;   // 0..63 (256 rows each)
    const int hh    = blockIdx.y;   // 0..15
    const int t = threadIdx.x;
    const int w = t >> 6, lane = t & 63;
    const int fr = lane & 15, fq = lane >> 4;

    {
        int r = t >> 2, c0 = (t & 3) << 4;
        #pragma unroll
        for (int k = 0; k < 4; ++k)
            *reinterpret_cast<float4*>(&PS[r * 64 + c0 + k * 4]) =
                *reinterpret_cast<const float4*>(&proj[(size_t)hh * 4096 + r * 64 + c0 + k * 4]);
    }
    __syncthreads();
    {
        int m = t >> 2, d0 = (t & 3) << 4;
        unsigned short hb[16], lb[16];
        #pragma unroll
        for (int j = 0; j < 16; ++j) {
            float v = PS[(d0 + j) * 64 + m];
            hb[j] = bf16_rne(v);
            lb[j] = bf16_rne(v - bf16_to_f32(hb[j]));
        }
        #pragma unroll
        for (int cp = 0; cp < 2; ++cp) {
            u16x8 vh, vl;
            #pragma unroll
            for (int j = 0; j < 8; ++j) { vh[j] = hb[cp * 8 + j]; vl[j] = lb[cp * 8 + j]; }
            int sidx = swz64(m, d0 + cp * 8);
            *reinterpret_cast<u16x8*>(&PJT_h[sidx]) = vh;
            *reinterpret_cast<u16x8*>(&PJT_l[sidx]) = vl;
        }
    }
    __syncthreads();

    f32x4 acc2[4] = {};
    float ksacc[4] = {0.f, 0.f, 0.f, 0.f};

    for (int sub = 0; sub < 4; ++sub) {
        const int rowL = chunk * 256 + sub * 64;   // global row

        float4 vv[4];
        {
            int l = t >> 2, c0 = (t & 3) << 4;
            #pragma unroll
            for (int k2 = 0; k2 < 4; ++k2)
                vv[k2] = *reinterpret_cast<const float4*>(
                    &kvb[(size_t)(rowL + l) * 2048 + 1024 + hh * 64 + c0 + k2 * 4]);
        }
        #pragma unroll
        for (int i = 0; i < 8; ++i) {
            int p = t + (i << 8);
            int l = p >> 5, i2 = p & 31;
            size_t base = (size_t)(rowL + l) * 2048 + hh * 64 + 2 * i2;
            float kr = kvb[base], ki = kvb[base + 1];
            int crow = (rowL + l) & 4095;
            float c = cosb[(size_t)crow * 32 + i2];
            float s = sinb[(size_t)crow * 32 + i2];
            float xr = kr * c - ki * s;
            float xi = kr * s + ki * c;
            unsigned short h0 = bf16_rne(xr), h1 = bf16_rne(xi);
            unsigned short l0 = bf16_rne(xr - bf16_to_f32(h0));
            unsigned short l1 = bf16_rne(xi - bf16_to_f32(h1));
            int sidx = swz64(l, 2 * i2);
            *reinterpret_cast<unsigned int*>(&KR_h[sidx]) = (unsigned)h0 | ((unsigned)h1 << 16);
            *reinterpret_cast<unsigned int*>(&KR_l[sidx]) = (unsigned)l0 | ((unsigned)l1 << 16);
        }
        if (t < 64) MS[t] = maskb[rowL + t];
        __syncthreads();   // B1

        f32x4 acc1[4] = {};
        #pragma unroll
        for (int ks = 0; ks < 2; ++ks) {
            bf16x8 ah = *reinterpret_cast<const bf16x8*>(&KR_h[swz64(16 * w + fr, ks * 32 + fq * 8)]);
            bf16x8 al = *reinterpret_cast<const bf16x8*>(&KR_l[swz64(16 * w + fr, ks * 32 + fq * 8)]);
            #pragma unroll
            for (int n = 0; n < 4; ++n) {
                bf16x8 bh = *reinterpret_cast<const bf16x8*>(&PJT_h[swz64(16 * n + fr, ks * 32 + fq * 8)]);
                bf16x8 bl = *reinterpret_cast<const bf16x8*>(&PJT_l[swz64(16 * n + fr, ks * 32 + fq * 8)]);
                acc1[n] = __builtin_amdgcn_mfma_f32_16x16x32_bf16(ah, bh, acc1[n], 0, 0, 0);
                acc1[n] = __builtin_amdgcn_mfma_f32_16x16x32_bf16(ah, bl, acc1[n], 0, 0, 0);
                acc1[n] = __builtin_amdgcn_mfma_f32_16x16x32_bf16(al, bh, acc1[n], 0, 0, 0);
            }
        }
        #pragma unroll
        for (int n = 0; n < 4; ++n) {
            unsigned short hb[4], lb[4];
            float ssum = 0.f;
            #pragma unroll
            for (int r = 0; r < 4; ++r) {
                int l = 16 * w + fq * 4 + r;
                float kp = fmaxf(acc1[n][r], 0.f) * MS[l];
                ssum += kp;
                hb[r] = bf16_rne(kp);
                lb[r] = bf16_rne(kp - bf16_to_f32(hb[r]));
            }
            ksacc[n] += ssum;
            int sidx = swz64(16 * n + fr, 16 * w + fq * 4);
            *reinterpret_cast<ushort4*>(&KPT_h[sidx]) = make_ushort4(hb[0], hb[1], hb[2], hb[3]);
            *reinterpret_cast<ushort4*>(&KPT_l[sidx]) = make_ushort4(lb[0], lb[1], lb[2], lb[3]);
        }
        __syncthreads();   // B2

        {
            float* VS = PS;
            int l = t >> 2, c0 = (t & 3) << 4;
            float mv = MS[l];
            #pragma unroll
            for (int k2 = 0; k2 < 4; ++k2) {
                float4 q = vv[k2];
                q.x *= mv; q.y *= mv; q.z *= mv; q.w *= mv;
                *reinterpret_cast<float4*>(&VS[l * 64 + c0 + k2 * 4]) = q;
            }
        }
        __syncthreads();   // B3

        {
            float* VS = PS;
            int d = t >> 2, l0 = (t & 3) << 4;
            unsigned short hb[16], lb[16];
            #pragma unroll
            for (int j = 0; j < 16; ++j) {
                float v = VS[(l0 + j) * 64 + d];
                hb[j] = bf16_rne(v);
                lb[j] = bf16_rne(v - bf16_to_f32(hb[j]));
            }
            #pragma unroll
            for (int cp = 0; cp < 2; ++cp) {
                u16x8 vh, vl;
                #pragma unroll
                for (int j = 0; j < 8; ++j) { vh[j] = hb[cp * 8 + j]; vl[j] = lb[cp * 8 + j]; }
                int sidx = swz64(d, l0 + cp * 8);
                *reinterpret_cast<u16x8*>(&VT_h[sidx]) = vh;
                *reinterpret_cast<u16x8*>(&VT_l[sidx]) = vl;
            }
        }
        __syncthreads();   // B4

        #pragma unroll
        for (int ks = 0; ks < 2; ++ks) {
            bf16x8 ah = *reinterpret_cast<const bf16x8*>(&KPT_h[swz64(16 * w + fr, ks * 32 + fq * 8)]);
            bf16x8 al = *reinterpret_cast<const bf16x8*>(&KPT_l[swz64(16 * w + fr, ks * 32 + fq * 8)]);
            #pragma unroll
            for (int n = 0; n < 4; ++n) {
                bf16x8 bh = *reinterpret_cast<const bf16x8*>(&VT_h[swz64(16 * n + fr, ks * 32 + fq * 8)]);
                bf16x8 bl = *reinterpret_cast<const bf16x8*>(&VT_l[swz64(16 * n + fr, ks * 32 + fq * 8)]);
                acc2[n] = __builtin_amdgcn_mfma_f32_16x16x32_bf16(ah, bh, acc2[n], 0, 0, 0);
                acc2[n] = __builtin_amdgcn_mfma_f32_16x16x32_bf16(ah, bl, acc2[n], 0, 0, 0);
                acc2[n] = __builtin_amdgcn_mfma_f32_16x16x32_bf16(al, bh, acc2[n], 0, 0, 0);
            }
        }
    }

    #pragma unroll
    for (int n = 0; n < 4; ++n) {
        float v = ksacc[n];
        v += __shfl_xor(v, 16);
        v += __shfl_xor(v, 32);
        if (fq == 0) KS[w * 64 + 16 * n + fr] = v;
    }
    __syncthreads();

    float* dst = partial + ((size_t)hh * 64 + chunk) * 4160;
    #pragma unroll
    for (int n = 0; n < 4; ++n)
        #pragma unroll
        for (int r = 0; r < 4; ++r) {
            int m = 16 * w + fq * 4 + r;
            int d = 16 * n + fr;
            dst[m * 64 + d] = acc2[n][r];
        }
    if (t < 64)
        dst[4096 + t] = KS[t] + KS[64 + t] + KS[128 + t] + KS[192 + t];
}

// Reduce 16 per-batch chunk partials -> kv (64x64) + ksum (64) per (b,h).
__global__ __launch_bounds__(256)
void kv_reduce_kernel(const float* __restrict__ partial, float* __restrict__ kvout)
{
    const int bh = blockIdx.x;          // b*16 + h
    const int b = bh >> 4, h = bh & 15;
    const int seg = blockIdx.y;         // 4160 = 4 segments x 1040
    for (int idx = seg * 1040 + threadIdx.x; idx < (seg + 1) * 1040; idx += 256) {
        float s = 0.f;
        for (int c = 0; c < 16; ++c)
            s += partial[((size_t)h * 64 + b * 16 + c) * 4160 + idx];
        kvout[(size_t)bh * 4160 + idx] = s;
    }
}

// ---------------------------------------------------------------------------
// context, full-batch (unchanged): grid (256, 16).
// ---------------------------------------------------------------------------
__global__ __launch_bounds__(256)
void context_kernel(const float* __restrict__ qb, const float* __restrict__ cosb,
                    const float* __restrict__ sinb, const float* __restrict__ proj,
                    const float* __restrict__ kvsum, unsigned short* __restrict__ ch,
                    unsigned short* __restrict__ cl)
{
    const int lt = blockIdx.x;   // 0..255
    const int h  = blockIdx.y;   // 0..15
    const int t = threadIdx.x;
    const int bh = (lt >> 6) * 16 + h;

    __shared__ float bufA[64][68];
    __shared__ float qp[64][68];
    __shared__ float pj[64][64];
    __shared__ float ksum[64];

    for (int i = t; i < 1024; i += 256)
        *reinterpret_cast<float4*>(&pj[0][0] + (size_t)i * 4) =
            *reinterpret_cast<const float4*>(proj + (size_t)h * 4096 + (size_t)i * 4);
    if (t < 64) ksum[t] = kvsum[(size_t)bh * 4160 + 4096 + t];

    const int rowL = lt * 64;            // global row
    #pragma unroll
    for (int i = 0; i < 8; ++i) {
        int p = t + i * 256;
        int l = p >> 5, i2 = p & 31;
        size_t base = (size_t)(rowL + l) * 1024 + h * HDIM + 2 * i2;
        float qr = qb[base], qi = qb[base + 1];
        int crow = (rowL + l) & 4095;
        float c = cosb[(size_t)crow * 32 + i2];
        float s = sinb[(size_t)crow * 32 + i2];
        bufA[l][2 * i2]     = qr * c - qi * s;
        bufA[l][2 * i2 + 1] = qr * s + qi * c;
    }
    __syncthreads();

    {
        int l = t >> 2, m0 = (t & 3) << 4;
        float a[16] = {};
        for (int d = 0; d < 64; ++d) {
            float ql = bufA[l][d];
            const float* pr = &pj[d][m0];
            #pragma unroll
            for (int j = 0; j < 16; ++j) a[j] = fmaf(ql, pr[j], a[j]);
        }
        #pragma unroll
        for (int j = 0; j < 16; ++j) qp[l][m0 + j] = fmaxf(a[j], 0.f);
    }
    __syncthreads();

    #pragma unroll
    for (int i = 0; i < 4; ++i) {
        int idx = t + i * 256;
        int mm = idx >> 4, dd = (idx & 15) << 2;
        *reinterpret_cast<float4*>(&bufA[mm][dd]) =
            *reinterpret_cast<const float4*>(&kvsum[(size_t)bh * 4160 + mm * 64 + dd]);
    }
    __syncthreads();

    {
        int l = t >> 2, d0 = (t & 3) << 4;
        float a[16] = {};
        float nrm = 0.f;
        for (int mm = 0; mm < 64; ++mm) {
            float qv = qp[l][mm];
            nrm = fmaf(qv, ksum[mm], nrm);
            const float* kr = &bufA[mm][d0];
            #pragma unroll
            for (int j = 0; j < 16; ++j) a[j] = fmaf(qv, kr[j], a[j]);
        }
        float inv = 1.0f / (nrm + 1e-4f);
        size_t orow = (size_t)(rowL + l) * 1024 + h * HDIM + d0;
        #pragma unroll
        for (int j4 = 0; j4 < 4; ++j4) {
            unsigned short hh2[4], ll2[4];
            #pragma unroll
            for (int j = 0; j < 4; ++j) {
                float v = a[j4 * 4 + j] * inv;
                hh2[j] = bf16_rne(v);
                ll2[j] = bf16_rne(v - bf16_to_f32(hh2[j]));
            }
            *reinterpret_cast<ushort4*>(&ch[orow + j4 * 4]) = make_ushort4(hh2[0], hh2[1], hh2[2], hh2[3]);
            *reinterpret_cast<ushort4*>(&cl[orow + j4 * 4]) = make_ushort4(ll2[0], ll2[1], ll2[2], ll2[3]);
        }
    }
}

extern "C" void kernel_launch(void* const* d_in, const int* in_sizes, int n_in,
                              void* d_out, int out_size, void* d_ws, size_t ws_size,
                              hipStream_t stream)
{
    const float* x    = (const float*)d_in[0];
    const float* fcos = (const float*)d_in[1];
    const float* fsin = (const float*)d_in[2];
    const float* mask = (const float*)d_in[3];
    const float* Wqkv = (const float*)d_in[4];
    const float* bqkv = (const float*)d_in[5];
    const float* proj = (const float*)d_in[6];
    const float* Wout = (const float*)d_in[7];
    const float* bout = (const float*)d_in[8];
    float* out = (float*)d_out;

    // Workspace (floats), 59,052,032 fl = 236.2 MB (< 256 MiB ws).
    float* W    = (float*)d_ws;          //  4,194,304 fl: weights hi/lo (transposed)
    float* XHL  = W + 4194304;           // 16,777,216 fl: x hi+lo bf16 -> later ctx hi+lo
    float* KVQ  = XHL + 16777216;        // 33,554,432 fl: KV fp32 [16384][2048] -> later Q [16384][1024]
    float* PART = KVQ + 33554432;        //  4,259,840 fl: partials [16][64][4160]
    float* KSUM = PART + 4259840;        //    266,240 fl: kvsum [64][4160]

    unsigned short* Wqh = (unsigned short*)W;       // Wqkv^T hi: [3072][1024]
    unsigned short* Wql = Wqh + 3145728;
    unsigned short* Woh = Wql + 3145728;            // Wout^T hi: [1024][1024]
    unsigned short* Wol = Woh + 1048576;
    unsigned short* xh  = (unsigned short*)XHL;     // also ctx hi (x dead by then)
    unsigned short* xl  = xh + 16777216;            // also ctx lo

    // Weight conversions (once per launch), transposed for B-operand K-contiguity
    convert_T_hilo<<<dim3(3072 / 64, 1024 / 64), 256, 0, stream>>>(Wqkv, Wqh, Wql, 1024, 3072);
    convert_T_hilo<<<dim3(1024 / 64, 1024 / 64), 256, 0, stream>>>(Wout, Woh, Wol, 1024, 1024);

    // x -> hi/lo, full batch
    convert_hilo<<<16384, 256, 0, stream>>>(x, xh, xl, ROWS * EMBED);

    // K,V = x @ Wqkv[:,1024:3072] + bqkv[1024:]  (full batch, [16384][2048])
    gemm3_kernel<<<dim3(2048 / 256, ROWS / 256), 512, 0, stream>>>(
        xh, xl, Wqh + (size_t)1024 * 1024, Wql + (size_t)1024 * 1024,
        bqkv + 1024, KVQ, 1024, 2048);

    // fused RoPE+proj+relu+mask -> kv partials (full batch)
    kv_mfma_kernel<<<dim3(64, 16), 256, 0, stream>>>(KVQ, fcos, fsin, mask, proj, PART);

    // reduce partials -> kv/ksum per (b,h)
    kv_reduce_kernel<<<dim3(64, 4), 256, 0, stream>>>(PART, KSUM);

    // Q = x @ Wqkv[:,0:1024] + bqkv[0:1024]  (overwrites KV region; KV dead)
    gemm3_kernel<<<dim3(1024 / 256, ROWS / 256), 512, 0, stream>>>(
        xh, xl, Wqh, Wql, bqkv, KVQ, 1024, 1024);

    // context + normalization; writes ctx hi/lo over xh/xl (x dead)
    context_kernel<<<dim3(256, 16), 256, 0, stream>>>(
        KVQ, fcos, fsin, proj, KSUM, xh, xl);

    // out = ctx @ Wout + bout
    gemm3_kernel<<<dim3(1024 / 256, ROWS / 256), 512, 0, stream>>>(
        xh, xl, Woh, Wol, bout, out, 1024, 1024);
}

// Round 13
// 505.104 us; speedup vs baseline: 1.1774x; 1.0241x over previous
//
#include <hip/hip_runtime.h>

#define LSEQ   4096
#define ROWS   16384             // 4 batches x 4096
#define EMBED  1024
#define NHEADS 16
#define HDIM   64
#define QKV_N  3072

typedef __attribute__((ext_vector_type(8))) short bf16x8;
typedef __attribute__((ext_vector_type(8))) unsigned short u16x8;
typedef __attribute__((ext_vector_type(4))) float f32x4;

// round-to-nearest-even fp32 -> bf16 (bit pattern), no header dependence
__device__ inline unsigned short bf16_rne(float x) {
    unsigned int u = __float_as_uint(x);
    unsigned int r = (u + 0x7fffu + ((u >> 16) & 1u)) >> 16;
    return (unsigned short)r;
}
__device__ inline float bf16_to_f32(unsigned short h) {
    return __uint_as_float(((unsigned int)h) << 16);
}

// swizzled short-index into a [64 rows][64 shorts] LDS tile (kv kernel)
__device__ __forceinline__ int swz64(int row, int s) {
    return row * 64 + ((((s >> 3) ^ (row & 7))) << 3) + (s & 7);
}

// ---------------------------------------------------------------------------
// Convert contiguous fp32 -> hi/lo bf16 arrays. n multiple of 1024.
// ---------------------------------------------------------------------------
__global__ __launch_bounds__(256)
void convert_hilo(const float* __restrict__ in, unsigned short* __restrict__ hi,
                  unsigned short* __restrict__ lo, int n)
{
    int i = (blockIdx.x * 256 + threadIdx.x) << 2;
    if (i >= n) return;
    float4 v = *reinterpret_cast<const float4*>(&in[i]);
    float a[4] = {v.x, v.y, v.z, v.w};
    unsigned short hh[4], ll[4];
    #pragma unroll
    for (int j = 0; j < 4; ++j) {
        hh[j] = bf16_rne(a[j]);
        ll[j] = bf16_rne(a[j] - bf16_to_f32(hh[j]));
    }
    *reinterpret_cast<ushort4*>(&hi[i]) = make_ushort4(hh[0], hh[1], hh[2], hh[3]);
    *reinterpret_cast<ushort4*>(&lo[i]) = make_ushort4(ll[0], ll[1], ll[2], ll[3]);
}

// ---------------------------------------------------------------------------
// Convert fp32 W[K][N] -> TRANSPOSED hi/lo bf16 Wt[N][K] (for B-operand).
// ---------------------------------------------------------------------------
__global__ __launch_bounds__(256)
void convert_T_hilo(const float* __restrict__ in, unsigned short* __restrict__ hi,
                    unsigned short* __restrict__ lo, int K, int N)
{
    __shared__ float tile[64][65];
    const int n0 = blockIdx.x * 64, k0 = blockIdx.y * 64;
    const int t = threadIdx.x;
    #pragma unroll
    for (int i = 0; i < 16; ++i) {
        int idx = t + i * 256;
        int r = idx >> 6, c = idx & 63;
        tile[r][c] = in[(size_t)(k0 + r) * N + n0 + c];
    }
    __syncthreads();
    #pragma unroll
    for (int i = 0; i < 16; ++i) {
        int idx = t + i * 256;
        int r = idx >> 6, c = idx & 63;
        float v = tile[c][r];
        unsigned short h = bf16_rne(v);
        unsigned short l = bf16_rne(v - bf16_to_f32(h));
        size_t o = (size_t)(n0 + r) * K + k0 + c;
        hi[o] = h;
        lo[o] = l;
    }
}

// ---------------------------------------------------------------------------
// bf16x3 split GEMM v10: 8-phase 256x256 (m201 template port), two fixes vs
// v9 whose p3 vmcnt stalled:
//  (1) prefetch issue schedule 4/4/0/0 (was 3/3/2/0): at the single
//      per-K-tile vmcnt(0) (end of p3), the newest load is >=2 phases
//      (~1860 cy) old -> covers ~900 cy HBM-miss latency (m126).
//  (2) bijective XCD chunk swizzle (T1, m204): consecutive blocks on an XCD
//      share the A row-panel (1 MB hi+lo, fits 4 MB XCD L2).
// Everything else identical to v9 (v8's measured-zero-conflict swizzle,
// raw s_barrier phases, lgkmcnt(0)+sched_barrier, setprio around MFMA).
// M,N multiples of 256; K multiple of 32. Grid nwg must be %8==0.
// ---------------------------------------------------------------------------
__global__ __launch_bounds__(512)
void gemm3_kernel(const unsigned short* __restrict__ Ah, const unsigned short* __restrict__ Al,
                  const unsigned short* __restrict__ Bh, const unsigned short* __restrict__ Bl,
                  const float* __restrict__ bias, float* __restrict__ C,
                  int K, int ldc)
{
    __shared__ __align__(16) unsigned short lds[2][32768];   // 128 KB

    const int t = threadIdx.x;
    const int wave = t >> 6, lane = t & 63;
    const int wr = wave >> 2, wc = wave & 3;     // wave tile: 128 rows x 64 cols
    const int fr = lane & 15, fq = lane >> 4;

    // bijective XCD chunk swizzle (nwg % 8 == 0 for all our grids)
    const int nwg = gridDim.x * gridDim.y;
    const int wg  = blockIdx.y * gridDim.x + blockIdx.x;
    const int swz = (wg & 7) * (nwg >> 3) + (wg >> 3);
    const int bx = swz % gridDim.x, by = swz / gridDim.x;
    const int rowBase = by * 256;
    const int colBase = bx * 256;

    // staging: waves 0-1 Ah, 2-3 Al, 4-5 Bh, 6-7 Bl; each wave a 128-row half.
    const int op = wave >> 1;
    const unsigned short* src = (op == 0) ? Ah : (op == 1) ? Al : (op == 2) ? Bh : Bl;
    const int tileRow0 = ((wave < 4) ? rowBase : colBase) + (wave & 1) * 128;
    const int subOff = op * 8192 + (wave & 1) * 4096;            // shorts
    const int sRow = lane >> 2;                                  // 0..15
    const int sChunk = (((lane & 3) ^ ((lane >> 3) & 3)) << 3);  // swizzled k-chunk

    f32x4 acc[8][4] = {};
    const int NT = K >> 5;

    // prologue: stage tile 0 into buffer 0 (full drain once via __syncthreads)
    #pragma unroll
    for (int i = 0; i < 8; ++i) {
        const unsigned short* g = src + (size_t)(tileRow0 + i * 16 + sRow) * K + sChunk;
        __builtin_amdgcn_global_load_lds(
            (const __attribute__((address_space(1))) void*)g,
            (__attribute__((address_space(3))) void*)&lds[0][subOff + i * 512], 16, 0, 0);
    }
    __syncthreads();

    for (int tI = 0; tI < NT; ++tI) {
        const int cur = tI & 1;
        const unsigned short* ldsC = lds[cur];
        const int k0 = (tI + 1) << 5;
        const bool pref = (tI + 1 < NT);

        bf16x8 bhf[4], blf[4];   // B fragments, register-resident across phases

        #pragma unroll
        for (int p = 0; p < 4; ++p) {
            // issue prefetch portion for tile t+1: 4 at p0, 4 at p1 (none later)
            if (pref && p < 2) {
                const int i0 = p * 4;
                #pragma unroll
                for (int i = 0; i < 4; ++i) {
                    const unsigned short* g =
                        src + (size_t)(tileRow0 + (i0 + i) * 16 + sRow) * K + k0 + sChunk;
                    __builtin_amdgcn_global_load_lds(
                        (const __attribute__((address_space(1))) void*)g,
                        (__attribute__((address_space(3))) void*)&lds[cur ^ 1][subOff + (i0 + i) * 512], 16, 0, 0);
                }
            }

            // ds_read this phase's A-frags (and all B-frags in phase 0)
            bf16x8 ahf[2], alf[2];
            #pragma unroll
            for (int mm = 0; mm < 2; ++mm) {
                int m = p * 2 + mm;
                int r = wr * 128 + m * 16 + fr;
                int off = r * 32 + ((fq ^ ((r >> 1) & 3)) << 3);
                ahf[mm] = *reinterpret_cast<const bf16x8*>(&ldsC[off]);
                alf[mm] = *reinterpret_cast<const bf16x8*>(&ldsC[8192 + off]);
            }
            if (p == 0) {
                #pragma unroll
                for (int n = 0; n < 4; ++n) {
                    int rb = wc * 64 + n * 16 + fr;
                    int off = rb * 32 + ((fq ^ ((rb >> 1) & 3)) << 3);
                    bhf[n] = *reinterpret_cast<const bf16x8*>(&ldsC[16384 + off]);
                    blf[n] = *reinterpret_cast<const bf16x8*>(&ldsC[24576 + off]);
                }
            }

            __builtin_amdgcn_s_barrier();                       // raw: no vm drain
            asm volatile("s_waitcnt lgkmcnt(0)" ::: "memory");
            __builtin_amdgcn_sched_barrier(0);                  // rule #18 fence
            __builtin_amdgcn_s_setprio(1);
            #pragma unroll
            for (int mm = 0; mm < 2; ++mm) {
                int m = p * 2 + mm;
                #pragma unroll
                for (int n = 0; n < 4; ++n) {
                    acc[m][n] = __builtin_amdgcn_mfma_f32_16x16x32_bf16(ahf[mm], bhf[n], acc[m][n], 0, 0, 0);
                    acc[m][n] = __builtin_amdgcn_mfma_f32_16x16x32_bf16(ahf[mm], blf[n], acc[m][n], 0, 0, 0);
                    acc[m][n] = __builtin_amdgcn_mfma_f32_16x16x32_bf16(alf[mm], bhf[n], acc[m][n], 0, 0, 0);
                }
            }
            __builtin_amdgcn_s_setprio(0);
            if (p == 3)  // tile t+1 staged; newest load is >=2 phases old
                asm volatile("s_waitcnt vmcnt(0)" ::: "memory");
            __builtin_amdgcn_s_barrier();
        }
    }

    // epilogue: C/D frag mapping col=lane&15, row=(lane>>4)*4+reg (m89-verified)
    #pragma unroll
    for (int m = 0; m < 8; ++m) {
        #pragma unroll
        for (int n = 0; n < 4; ++n) {
            int col = colBase + wc * 64 + n * 16 + fr;
            float bv = bias[col];
            #pragma unroll
            for (int r = 0; r < 4; ++r) {
                int row = rowBase + wr * 128 + m * 16 + fq * 4 + r;
                C[(size_t)row * ldc + col] = acc[m][n][r] + bv;
            }
        }
    }
}

// ---------------------------------------------------------------------------
// kv MFMA kernel, full-batch (unchanged): per (256-row chunk, head).
// ---------------------------------------------------------------------------
__global__ __launch_bounds__(256)
void kv_mfma_kernel(const float* __restrict__ kvb, const float* __restrict__ cosb,
                    const float* __restrict__ sinb, const float* __restrict__ maskb,
                    const float* __restrict__ proj, float* __restrict__ partial)
{
    __shared__ __align__(16) char smem[66816];
    unsigned short* KR_h  = (unsigned short*)smem;
    unsigned short* KR_l  = (unsigned short*)(smem + 8192);
    float*          PS    = (float*)smem;                    // aliases KR (fp32 [64][64])
    unsigned short* PJT_h = (unsigned short*)(smem + 16384);
    unsigned short* PJT_l = (unsigned short*)(smem + 24576);
    unsigned short* KPT_h = (unsigned short*)(smem + 32768);
    unsigned short* KPT_l = (unsigned short*)(smem + 40960);
    unsigned short* VT_h  = (unsigned short*)(smem + 49152);
    unsigned short* VT_l  = (unsigned short*)(smem + 57344);
    float*          MS    = (float*)(smem + 65536);
    float*          KS    = (float*)(smem + 65792);

    const int chunk = blockIdx.x;   // 0..63 (256 rows each)
    const int hh    = blockIdx.y;   // 0..15
    const int t = threadIdx.x;
    const int w = t >> 6, lane = t & 63;
    const int fr = lane & 15, fq = lane >> 4;

    {
        int r = t >> 2, c0 = (t & 3) << 4;
        #pragma unroll
        for (int k = 0; k < 4; ++k)
            *reinterpret_cast<float4*>(&PS[r * 64 + c0 + k * 4]) =
                *reinterpret_cast<const float4*>(&proj[(size_t)hh * 4096 + r * 64 + c0 + k * 4]);
    }
    __syncthreads();
    {
        int m = t >> 2, d0 = (t & 3) << 4;
        unsigned short hb[16], lb[16];
        #pragma unroll
        for (int j = 0; j < 16; ++j) {
            float v = PS[(d0 + j) * 64 + m];
            hb[j] = bf16_rne(v);
            lb[j] = bf16_rne(v - bf16_to_f32(hb[j]));
        }
        #pragma unroll
        for (int cp = 0; cp < 2; ++cp) {
            u16x8 vh, vl;
            #pragma unroll
            for (int j = 0; j < 8; ++j) { vh[j] = hb[cp * 8 + j]; vl[j] = lb[cp * 8 + j]; }
            int sidx = swz64(m, d0 + cp * 8);
            *reinterpret_cast<u16x8*>(&PJT_h[sidx]) = vh;
            *reinterpret_cast<u16x8*>(&PJT_l[sidx]) = vl;
        }
    }
    __syncthreads();

    f32x4 acc2[4] = {};
    float ksacc[4] = {0.f, 0.f, 0.f, 0.f};

    for (int sub = 0; sub < 4; ++sub) {
        const int rowL = chunk * 256 + sub * 64;   // global row

        float4 vv[4];
        {
            int l = t >> 2, c0 = (t & 3) << 4;
            #pragma unroll
            for (int k2 = 0; k2 < 4; ++k2)
                vv[k2] = *reinterpret_cast<const float4*>(
                    &kvb[(size_t)(rowL + l) * 2048 + 1024 + hh * 64 + c0 + k2 * 4]);
        }
        #pragma unroll
        for (int i = 0; i < 8; ++i) {
            int p = t + (i << 8);
            int l = p >> 5, i2 = p & 31;
            size_t base = (size_t)(rowL + l) * 2048 + hh * 64 + 2 * i2;
            float kr = kvb[base], ki = kvb[base + 1];
            int crow = (rowL + l) & 4095;
            float c = cosb[(size_t)crow * 32 + i2];
            float s = sinb[(size_t)crow * 32 + i2];
            float xr = kr * c - ki * s;
            float xi = kr * s + ki * c;
            unsigned short h0 = bf16_rne(xr), h1 = bf16_rne(xi);
            unsigned short l0 = bf16_rne(xr - bf16_to_f32(h0));
            unsigned short l1 = bf16_rne(xi - bf16_to_f32(h1));
            int sidx = swz64(l, 2 * i2);
            *reinterpret_cast<unsigned int*>(&KR_h[sidx]) = (unsigned)h0 | ((unsigned)h1 << 16);
            *reinterpret_cast<unsigned int*>(&KR_l[sidx]) = (unsigned)l0 | ((unsigned)l1 << 16);
        }
        if (t < 64) MS[t] = maskb[rowL + t];
        __syncthreads();   // B1

        f32x4 acc1[4] = {};
        #pragma unroll
        for (int ks = 0; ks < 2; ++ks) {
            bf16x8 ah = *reinterpret_cast<const bf16x8*>(&KR_h[swz64(16 * w + fr, ks * 32 + fq * 8)]);
            bf16x8 al = *reinterpret_cast<const bf16x8*>(&KR_l[swz64(16 * w + fr, ks * 32 + fq * 8)]);
            #pragma unroll
            for (int n = 0; n < 4; ++n) {
                bf16x8 bh = *reinterpret_cast<const bf16x8*>(&PJT_h[swz64(16 * n + fr, ks * 32 + fq * 8)]);
                bf16x8 bl = *reinterpret_cast<const bf16x8*>(&PJT_l[swz64(16 * n + fr, ks * 32 + fq * 8)]);
                acc1[n] = __builtin_amdgcn_mfma_f32_16x16x32_bf16(ah, bh, acc1[n], 0, 0, 0);
                acc1[n] = __builtin_amdgcn_mfma_f32_16x16x32_bf16(ah, bl, acc1[n], 0, 0, 0);
                acc1[n] = __builtin_amdgcn_mfma_f32_16x16x32_bf16(al, bh, acc1[n], 0, 0, 0);
            }
        }
        #pragma unroll
        for (int n = 0; n < 4; ++n) {
            unsigned short hb[4], lb[4];
            float ssum = 0.f;
            #pragma unroll
            for (int r = 0; r < 4; ++r) {
                int l = 16 * w + fq * 4 + r;
                float kp = fmaxf(acc1[n][r], 0.f) * MS[l];
                ssum += kp;
                hb[r] = bf16_rne(kp);
                lb[r] = bf16_rne(kp - bf16_to_f32(hb[r]));
            }
            ksacc[n] += ssum;
            int sidx = swz64(16 * n + fr, 16 * w + fq * 4);
            *reinterpret_cast<ushort4*>(&KPT_h[sidx]) = make_ushort4(hb[0], hb[1], hb[2], hb[3]);
            *reinterpret_cast<ushort4*>(&KPT_l[sidx]) = make_ushort4(lb[0], lb[1], lb[2], lb[3]);
        }
        __syncthreads();   // B2

        {
            float* VS = PS;
            int l = t >> 2, c0 = (t & 3) << 4;
            float mv = MS[l];
            #pragma unroll
            for (int k2 = 0; k2 < 4; ++k2) {
                float4 q = vv[k2];
                q.x *= mv; q.y *= mv; q.z *= mv; q.w *= mv;
                *reinterpret_cast<float4*>(&VS[l * 64 + c0 + k2 * 4]) = q;
            }
        }
        __syncthreads();   // B3

        {
            float* VS = PS;
            int d = t >> 2, l0 = (t & 3) << 4;
            unsigned short hb[16], lb[16];
            #pragma unroll
            for (int j = 0; j < 16; ++j) {
                float v = VS[(l0 + j) * 64 + d];
                hb[j] = bf16_rne(v);
                lb[j] = bf16_rne(v - bf16_to_f32(hb[j]));
            }
            #pragma unroll
            for (int cp = 0; cp < 2; ++cp) {
                u16x8 vh, vl;
                #pragma unroll
                for (int j = 0; j < 8; ++j) { vh[j] = hb[cp * 8 + j]; vl[j] = lb[cp * 8 + j]; }
                int sidx = swz64(d, l0 + cp * 8);
                *reinterpret_cast<u16x8*>(&VT_h[sidx]) = vh;
                *reinterpret_cast<u16x8*>(&VT_l[sidx]) = vl;
            }
        }
        __syncthreads();   // B4

        #pragma unroll
        for (int ks = 0; ks < 2; ++ks) {
            bf16x8 ah = *reinterpret_cast<const bf16x8*>(&KPT_h[swz64(16 * w + fr, ks * 32 + fq * 8)]);
            bf16x8 al = *reinterpret_cast<const bf16x8*>(&KPT_l[swz64(16 * w + fr, ks * 32 + fq * 8)]);
            #pragma unroll
            for (int n = 0; n < 4; ++n) {
                bf16x8 bh = *reinterpret_cast<const bf16x8*>(&VT_h[swz64(16 * n + fr, ks * 32 + fq * 8)]);
                bf16x8 bl = *reinterpret_cast<const bf16x8*>(&VT_l[swz64(16 * n + fr, ks * 32 + fq * 8)]);
                acc2[n] = __builtin_amdgcn_mfma_f32_16x16x32_bf16(ah, bh, acc2[n], 0, 0, 0);
                acc2[n] = __builtin_amdgcn_mfma_f32_16x16x32_bf16(ah, bl, acc2[n], 0, 0, 0);
                acc2[n] = __builtin_amdgcn_mfma_f32_16x16x32_bf16(al, bh, acc2[n], 0, 0, 0);
            }
        }
    }

    #pragma unroll
    for (int n = 0; n < 4; ++n) {
        float v = ksacc[n];
        v += __shfl_xor(v, 16);
        v += __shfl_xor(v, 32);
        if (fq == 0) KS[w * 64 + 16 * n + fr] = v;
    }
    __syncthreads();

    float* dst = partial + ((size_t)hh * 64 + chunk) * 4160;
    #pragma unroll
    for (int n = 0; n < 4; ++n)
        #pragma unroll
        for (int r = 0; r < 4; ++r) {
            int m = 16 * w + fq * 4 + r;
            int d = 16 * n + fr;
            dst[m * 64 + d] = acc2[n][r];
        }
    if (t < 64)
        dst[4096 + t] = KS[t] + KS[64 + t] + KS[128 + t] + KS[192 + t];
}

// Reduce 16 per-batch chunk partials -> kv (64x64) + ksum (64) per (b,h).
__global__ __launch_bounds__(256)
void kv_reduce_kernel(const float* __restrict__ partial, float* __restrict__ kvout)
{
    const int bh = blockIdx.x;          // b*16 + h
    const int b = bh >> 4, h = bh & 15;
    const int seg = blockIdx.y;         // 4160 = 4 segments x 1040
    for (int idx = seg * 1040 + threadIdx.x; idx < (seg + 1) * 1040; idx += 256) {
        float s = 0.f;
        for (int c = 0; c < 16; ++c)
            s += partial[((size_t)h * 64 + b * 16 + c) * 4160 + idx];
        kvout[(size_t)bh * 4160 + idx] = s;
    }
}

// ---------------------------------------------------------------------------
// context, full-batch (unchanged): grid (256, 16).
// ---------------------------------------------------------------------------
__global__ __launch_bounds__(256)
void context_kernel(const float* __restrict__ qb, const float* __restrict__ cosb,
                    const float* __restrict__ sinb, const float* __restrict__ proj,
                    const float* __restrict__ kvsum, unsigned short* __restrict__ ch,
                    unsigned short* __restrict__ cl)
{
    const int lt = blockIdx.x;   // 0..255
    const int h  = blockIdx.y;   // 0..15
    const int t = threadIdx.x;
    const int bh = (lt >> 6) * 16 + h;

    __shared__ float bufA[64][68];
    __shared__ float qp[64][68];
    __shared__ float pj[64][64];
    __shared__ float ksum[64];

    for (int i = t; i < 1024; i += 256)
        *reinterpret_cast<float4*>(&pj[0][0] + (size_t)i * 4) =
            *reinterpret_cast<const float4*>(proj + (size_t)h * 4096 + (size_t)i * 4);
    if (t < 64) ksum[t] = kvsum[(size_t)bh * 4160 + 4096 + t];

    const int rowL = lt * 64;            // global row
    #pragma unroll
    for (int i = 0; i < 8; ++i) {
        int p = t + i * 256;
        int l = p >> 5, i2 = p & 31;
        size_t base = (size_t)(rowL + l) * 1024 + h * HDIM + 2 * i2;
        float qr = qb[base], qi = qb[base + 1];
        int crow = (rowL + l) & 4095;
        float c = cosb[(size_t)crow * 32 + i2];
        float s = sinb[(size_t)crow * 32 + i2];
        bufA[l][2 * i2]     = qr * c - qi * s;
        bufA[l][2 * i2 + 1] = qr * s + qi * c;
    }
    __syncthreads();

    {
        int l = t >> 2, m0 = (t & 3) << 4;
        float a[16] = {};
        for (int d = 0; d < 64; ++d) {
            float ql = bufA[l][d];
            const float* pr = &pj[d][m0];
            #pragma unroll
            for (int j = 0; j < 16; ++j) a[j] = fmaf(ql, pr[j], a[j]);
        }
        #pragma unroll
        for (int j = 0; j < 16; ++j) qp[l][m0 + j] = fmaxf(a[j], 0.f);
    }
    __syncthreads();

    #pragma unroll
    for (int i = 0; i < 4; ++i) {
        int idx = t + i * 256;
        int mm = idx >> 4, dd = (idx & 15) << 2;
        *reinterpret_cast<float4*>(&bufA[mm][dd]) =
            *reinterpret_cast<const float4*>(&kvsum[(size_t)bh * 4160 + mm * 64 + dd]);
    }
    __syncthreads();

    {
        int l = t >> 2, d0 = (t & 3) << 4;
        float a[16] = {};
        float nrm = 0.f;
        for (int mm = 0; mm < 64; ++mm) {
            float qv = qp[l][mm];
            nrm = fmaf(qv, ksum[mm], nrm);
            const float* kr = &bufA[mm][d0];
            #pragma unroll
            for (int j = 0; j < 16; ++j) a[j] = fmaf(qv, kr[j], a[j]);
        }
        float inv = 1.0f / (nrm + 1e-4f);
        size_t orow = (size_t)(rowL + l) * 1024 + h * HDIM + d0;
        #pragma unroll
        for (int j4 = 0; j4 < 4; ++j4) {
            unsigned short hh2[4], ll2[4];
            #pragma unroll
            for (int j = 0; j < 4; ++j) {
                float v = a[j4 * 4 + j] * inv;
                hh2[j] = bf16_rne(v);
                ll2[j] = bf16_rne(v - bf16_to_f32(hh2[j]));
            }
            *reinterpret_cast<ushort4*>(&ch[orow + j4 * 4]) = make_ushort4(hh2[0], hh2[1], hh2[2], hh2[3]);
            *reinterpret_cast<ushort4*>(&cl[orow + j4 * 4]) = make_ushort4(ll2[0], ll2[1], ll2[2], ll2[3]);
        }
    }
}

extern "C" void kernel_launch(void* const* d_in, const int* in_sizes, int n_in,
                              void* d_out, int out_size, void* d_ws, size_t ws_size,
                              hipStream_t stream)
{
    const float* x    = (const float*)d_in[0];
    const float* fcos = (const float*)d_in[1];
    const float* fsin = (const float*)d_in[2];
    const float* mask = (const float*)d_in[3];
    const float* Wqkv = (const float*)d_in[4];
    const float* bqkv = (const float*)d_in[5];
    const float* proj = (const float*)d_in[6];
    const float* Wout = (const float*)d_in[7];
    const float* bout = (const float*)d_in[8];
    float* out = (float*)d_out;

    // Workspace (floats), 59,052,032 fl = 236.2 MB (< 256 MiB ws).
    float* W    = (float*)d_ws;          //  4,194,304 fl: weights hi/lo (transposed)
    float* XHL  = W + 4194304;           // 16,777,216 fl: x hi+lo bf16 -> later ctx hi+lo
    float* KVQ  = XHL + 16777216;        // 33,554,432 fl: KV fp32 [16384][2048] -> later Q [16384][1024]
    float* PART = KVQ + 33554432;        //  4,259,840 fl: partials [16][64][4160]
    float* KSUM = PART + 4259840;        //    266,240 fl: kvsum [64][4160]

    unsigned short* Wqh = (unsigned short*)W;       // Wqkv^T hi: [3072][1024]
    unsigned short* Wql = Wqh + 3145728;
    unsigned short* Woh = Wql + 3145728;            // Wout^T hi: [1024][1024]
    unsigned short* Wol = Woh + 1048576;
    unsigned short* xh  = (unsigned short*)XHL;     // also ctx hi (x dead by then)
    unsigned short* xl  = xh + 16777216;            // also ctx lo

    // Weight conversions (once per launch), transposed for B-operand K-contiguity
    convert_T_hilo<<<dim3(3072 / 64, 1024 / 64), 256, 0, stream>>>(Wqkv, Wqh, Wql, 1024, 3072);
    convert_T_hilo<<<dim3(1024 / 64, 1024 / 64), 256, 0, stream>>>(Wout, Woh, Wol, 1024, 1024);

    // x -> hi/lo, full batch
    convert_hilo<<<16384, 256, 0, stream>>>(x, xh, xl, ROWS * EMBED);

    // K,V = x @ Wqkv[:,1024:3072] + bqkv[1024:]  (full batch, [16384][2048])
    gemm3_kernel<<<dim3(2048 / 256, ROWS / 256), 512, 0, stream>>>(
        xh, xl, Wqh + (size_t)1024 * 1024, Wql + (size_t)1024 * 1024,
        bqkv + 1024, KVQ, 1024, 2048);

    // fused RoPE+proj+relu+mask -> kv partials (full batch)
    kv_mfma_kernel<<<dim3(64, 16), 256, 0, stream>>>(KVQ, fcos, fsin, mask, proj, PART);

    // reduce partials -> kv/ksum per (b,h)
    kv_reduce_kernel<<<dim3(64, 4), 256, 0, stream>>>(PART, KSUM);

    // Q = x @ Wqkv[:,0:1024] + bqkv[0:1024]  (overwrites KV region; KV dead)
    gemm3_kernel<<<dim3(1024 / 256, ROWS / 256), 512, 0, stream>>>(
        xh, xl, Wqh, Wql, bqkv, KVQ, 1024, 1024);

    // context + normalization; writes ctx hi/lo over xh/xl (x dead)
    context_kernel<<<dim3(256, 16), 256, 0, stream>>>(
        KVQ, fcos, fsin, proj, KSUM, xh, xl);

    // out = ctx @ Wout + bout
    gemm3_kernel<<<dim3(1024 / 256, ROWS / 256), 512, 0, stream>>>(
        xh, xl, Woh, Wol, bout, out, 1024, 1024);
}

// Round 14
// 503.035 us; speedup vs baseline: 1.1823x; 1.0041x over previous
//
#include <hip/hip_runtime.h>

#define LSEQ   4096
#define ROWS   16384             // 4 batches x 4096
#define EMBED  1024
#define NHEADS 16
#define HDIM   64
#define QKV_N  3072

typedef __attribute__((ext_vector_type(8))) short bf16x8;
typedef __attribute__((ext_vector_type(8))) unsigned short u16x8;
typedef __attribute__((ext_vector_type(4))) float f32x4;

// round-to-nearest-even fp32 -> bf16 (bit pattern), no header dependence
__device__ inline unsigned short bf16_rne(float x) {
    unsigned int u = __float_as_uint(x);
    unsigned int r = (u + 0x7fffu + ((u >> 16) & 1u)) >> 16;
    return (unsigned short)r;
}
__device__ inline float bf16_to_f32(unsigned short h) {
    return __uint_as_float(((unsigned int)h) << 16);
}

// swizzled short-index into a [64 rows][64 shorts] LDS tile (kv kernel)
__device__ __forceinline__ int swz64(int row, int s) {
    return row * 64 + ((((s >> 3) ^ (row & 7))) << 3) + (s & 7);
}

// ---------------------------------------------------------------------------
// Convert contiguous fp32 -> hi/lo bf16 arrays. n multiple of 1024.
// ---------------------------------------------------------------------------
__global__ __launch_bounds__(256)
void convert_hilo(const float* __restrict__ in, unsigned short* __restrict__ hi,
                  unsigned short* __restrict__ lo, int n)
{
    int i = (blockIdx.x * 256 + threadIdx.x) << 2;
    if (i >= n) return;
    float4 v = *reinterpret_cast<const float4*>(&in[i]);
    float a[4] = {v.x, v.y, v.z, v.w};
    unsigned short hh[4], ll[4];
    #pragma unroll
    for (int j = 0; j < 4; ++j) {
        hh[j] = bf16_rne(a[j]);
        ll[j] = bf16_rne(a[j] - bf16_to_f32(hh[j]));
    }
    *reinterpret_cast<ushort4*>(&hi[i]) = make_ushort4(hh[0], hh[1], hh[2], hh[3]);
    *reinterpret_cast<ushort4*>(&lo[i]) = make_ushort4(ll[0], ll[1], ll[2], ll[3]);
}

// ---------------------------------------------------------------------------
// Convert fp32 W[K][N] -> TRANSPOSED hi/lo bf16 Wt[N][K] (for B-operand).
// ---------------------------------------------------------------------------
__global__ __launch_bounds__(256)
void convert_T_hilo(const float* __restrict__ in, unsigned short* __restrict__ hi,
                    unsigned short* __restrict__ lo, int K, int N)
{
    __shared__ float tile[64][65];
    const int n0 = blockIdx.x * 64, k0 = blockIdx.y * 64;
    const int t = threadIdx.x;
    #pragma unroll
    for (int i = 0; i < 16; ++i) {
        int idx = t + i * 256;
        int r = idx >> 6, c = idx & 63;
        tile[r][c] = in[(size_t)(k0 + r) * N + n0 + c];
    }
    __syncthreads();
    #pragma unroll
    for (int i = 0; i < 16; ++i) {
        int idx = t + i * 256;
        int r = idx >> 6, c = idx & 63;
        float v = tile[c][r];
        unsigned short h = bf16_rne(v);
        unsigned short l = bf16_rne(v - bf16_to_f32(h));
        size_t o = (size_t)(n0 + r) * K + k0 + c;
        hi[o] = h;
        lo[o] = l;
    }
}

// ---------------------------------------------------------------------------
// bf16x3 split GEMM v11: counted-vmcnt pipeline (T4, m201/m218 mechanism).
// 256x256 block, 8 waves (2M x 4N), per-wave 128x64 = 8x4 frags of
// mfma_f32_16x16x32_bf16, BK=32, LDS 128 KB dbuf. v8's measured-zero-conflict
// swizzle unchanged.
// Staging roles: waves 0-3 stage A(h,l) 128-row halves with PHASE-ALIGNED
// issues (2 per phase; issue pair {2p,2p+1} = rows phase p of the NEXT tile
// reads) -> steady state: outstanding=8 at every phase end, oldest 2 = next
// phase's data -> uniform s_waitcnt vmcnt(6) (never 0). Waves 4-7 stage B:
// all 8 issues at p0, vmcnt(0) only at p3 (3 phases old, pre-satisfied).
// Last tile prefetches tile 0 (dummy, never read) to keep counts invariant.
// One barrier per phase; publish = stager's own vmcnt + barrier.
// M,N multiples of 256; K = 1024 (NT=32). Grid nwg % 8 == 0 (XCD swizzle).
// ---------------------------------------------------------------------------
__global__ __launch_bounds__(512)
void gemm3_kernel(const unsigned short* __restrict__ Ah, const unsigned short* __restrict__ Al,
                  const unsigned short* __restrict__ Bh, const unsigned short* __restrict__ Bl,
                  const float* __restrict__ bias, float* __restrict__ C,
                  int K, int ldc)
{
    __shared__ __align__(16) unsigned short lds[2][32768];   // 128 KB

    const int t = threadIdx.x;
    const int wave = t >> 6, lane = t & 63;
    const int wr = wave >> 2, wc = wave & 3;     // wave tile: 128 rows x 64 cols
    const int fr = lane & 15, fq = lane >> 4;

    // bijective XCD chunk swizzle (nwg % 8 == 0 for all our grids)
    const int nwg = gridDim.x * gridDim.y;
    const int wg  = blockIdx.y * gridDim.x + blockIdx.x;
    const int swz = (wg & 7) * (nwg >> 3) + (wg >> 3);
    const int bx = swz % gridDim.x, by = swz / gridDim.x;
    const int rowBase = by * 256;
    const int colBase = bx * 256;

    // staging: waves 0-1 Ah, 2-3 Al, 4-5 Bh, 6-7 Bl; each wave a 128-row half.
    const int op = wave >> 1;
    const bool isA = (wave < 4);
    const unsigned short* src = (op == 0) ? Ah : (op == 1) ? Al : (op == 2) ? Bh : Bl;
    const int tileRow0 = (isA ? rowBase : colBase) + (wave & 1) * 128;
    const int subOff = op * 8192 + (wave & 1) * 4096;            // shorts
    const int sRow = lane >> 2;                                  // 0..15
    const int sChunk = (((lane & 3) ^ ((lane >> 3) & 3)) << 3);  // swizzled k-chunk

    f32x4 acc[8][4] = {};
    const int NT = K >> 5;

    // prologue: stage tile 0 into buffer 0 (full drain once)
    #pragma unroll
    for (int i = 0; i < 8; ++i) {
        const unsigned short* g = src + (size_t)(tileRow0 + i * 16 + sRow) * K + sChunk;
        __builtin_amdgcn_global_load_lds(
            (const __attribute__((address_space(1))) void*)g,
            (__attribute__((address_space(3))) void*)&lds[0][subOff + i * 512], 16, 0, 0);
    }
    __syncthreads();

    for (int tI = 0; tI < NT; ++tI) {
        const int cur = tI & 1;
        const unsigned short* ldsC = lds[cur];
        // prefetch tile index (dummy tile-0 prefetch on last iter keeps vmcnt
        // invariants uniform; lands in buffer cur^1 which is never read again)
        const int kn = ((tI + 1 < NT) ? (tI + 1) : 0) << 5;

        bf16x8 bhf[4], blf[4];   // B fragments, register-resident across phases

        #pragma unroll
        for (int p = 0; p < 4; ++p) {
            // 1. ds_read this phase's A-frags (and all B-frags in phase 0);
            //    data published at previous phase's barrier.
            bf16x8 ahf[2], alf[2];
            #pragma unroll
            for (int mm = 0; mm < 2; ++mm) {
                int m = p * 2 + mm;
                int r = wr * 128 + m * 16 + fr;
                int off = r * 32 + ((fq ^ ((r >> 1) & 3)) << 3);
                ahf[mm] = *reinterpret_cast<const bf16x8*>(&ldsC[off]);
                alf[mm] = *reinterpret_cast<const bf16x8*>(&ldsC[8192 + off]);
            }
            if (p == 0) {
                #pragma unroll
                for (int n = 0; n < 4; ++n) {
                    int rb = wc * 64 + n * 16 + fr;
                    int off = rb * 32 + ((fq ^ ((rb >> 1) & 3)) << 3);
                    bhf[n] = *reinterpret_cast<const bf16x8*>(&ldsC[16384 + off]);
                    blf[n] = *reinterpret_cast<const bf16x8*>(&ldsC[24576 + off]);
                }
            }

            // 2. issue prefetch: A-stagers 2/phase (phase-aligned pairs);
            //    B-stagers all 8 at p0.
            if (isA) {
                #pragma unroll
                for (int i = 0; i < 2; ++i) {
                    const int ii = p * 2 + i;
                    const unsigned short* g =
                        src + (size_t)(tileRow0 + ii * 16 + sRow) * K + kn + sChunk;
                    __builtin_amdgcn_global_load_lds(
                        (const __attribute__((address_space(1))) void*)g,
                        (__attribute__((address_space(3))) void*)&lds[cur ^ 1][subOff + ii * 512], 16, 0, 0);
                }
            } else if (p == 0) {
                #pragma unroll
                for (int ii = 0; ii < 8; ++ii) {
                    const unsigned short* g =
                        src + (size_t)(tileRow0 + ii * 16 + sRow) * K + kn + sChunk;
                    __builtin_amdgcn_global_load_lds(
                        (const __attribute__((address_space(1))) void*)g,
                        (__attribute__((address_space(3))) void*)&lds[cur ^ 1][subOff + ii * 512], 16, 0, 0);
                }
            }

            // 3. counted waits (T4): A-stagers vmcnt(6) every phase;
            //    B-stagers full drain only at p3 (3 phases old).
            __builtin_amdgcn_sched_barrier(0);   // pin issues above the waitcnt
            if (isA) {
                asm volatile("s_waitcnt vmcnt(6) lgkmcnt(0)" ::: "memory");
            } else if (p == 3) {
                asm volatile("s_waitcnt vmcnt(0) lgkmcnt(0)" ::: "memory");
            } else {
                asm volatile("s_waitcnt lgkmcnt(0)" ::: "memory");
            }
            __builtin_amdgcn_s_barrier();        // publish
            __builtin_amdgcn_sched_barrier(0);   // rule #18 fence before MFMA

            // 4. MFMA cluster (T5)
            __builtin_amdgcn_s_setprio(1);
            #pragma unroll
            for (int mm = 0; mm < 2; ++mm) {
                int m = p * 2 + mm;
                #pragma unroll
                for (int n = 0; n < 4; ++n) {
                    acc[m][n] = __builtin_amdgcn_mfma_f32_16x16x32_bf16(ahf[mm], bhf[n], acc[m][n], 0, 0, 0);
                    acc[m][n] = __builtin_amdgcn_mfma_f32_16x16x32_bf16(ahf[mm], blf[n], acc[m][n], 0, 0, 0);
                    acc[m][n] = __builtin_amdgcn_mfma_f32_16x16x32_bf16(alf[mm], bhf[n], acc[m][n], 0, 0, 0);
                }
            }
            __builtin_amdgcn_s_setprio(0);
        }
    }

    // epilogue: C/D frag mapping col=lane&15, row=(lane>>4)*4+reg (m89-verified)
    #pragma unroll
    for (int m = 0; m < 8; ++m) {
        #pragma unroll
        for (int n = 0; n < 4; ++n) {
            int col = colBase + wc * 64 + n * 16 + fr;
            float bv = bias[col];
            #pragma unroll
            for (int r = 0; r < 4; ++r) {
                int row = rowBase + wr * 128 + m * 16 + fq * 4 + r;
                C[(size_t)row * ldc + col] = acc[m][n][r] + bv;
            }
        }
    }
}

// ---------------------------------------------------------------------------
// kv MFMA kernel, full-batch (unchanged): per (256-row chunk, head).
// ---------------------------------------------------------------------------
__global__ __launch_bounds__(256)
void kv_mfma_kernel(const float* __restrict__ kvb, const float* __restrict__ cosb,
                    const float* __restrict__ sinb, const float* __restrict__ maskb,
                    const float* __restrict__ proj, float* __restrict__ partial)
{
    __shared__ __align__(16) char smem[66816];
    unsigned short* KR_h  = (unsigned short*)smem;
    unsigned short* KR_l  = (unsigned short*)(smem + 8192);
    float*          PS    = (float*)smem;                    // aliases KR (fp32 [64][64])
    unsigned short* PJT_h = (unsigned short*)(smem + 16384);
    unsigned short* PJT_l = (unsigned short*)(smem + 24576);
    unsigned short* KPT_h = (unsigned short*)(smem + 32768);
    unsigned short* KPT_l = (unsigned short*)(smem + 40960);
    unsigned short* VT_h  = (unsigned short*)(smem + 49152);
    unsigned short* VT_l  = (unsigned short*)(smem + 57344);
    float*          MS    = (float*)(smem + 65536);
    float*          KS    = (float*)(smem + 65792);

    const int chunk = blockIdx.x;   // 0..63 (256 rows each)
    const int hh    = blockIdx.y;   // 0..15
    const int t = threadIdx.x;
    const int w = t >> 6, lane = t & 63;
    const int fr = lane & 15, fq = lane >> 4;

    {
        int r = t >> 2, c0 = (t & 3) << 4;
        #pragma unroll
        for (int k = 0; k < 4; ++k)
            *reinterpret_cast<float4*>(&PS[r * 64 + c0 + k * 4]) =
                *reinterpret_cast<const float4*>(&proj[(size_t)hh * 4096 + r * 64 + c0 + k * 4]);
    }
    __syncthreads();
    {
        int m = t >> 2, d0 = (t & 3) << 4;
        unsigned short hb[16], lb[16];
        #pragma unroll
        for (int j = 0; j < 16; ++j) {
            float v = PS[(d0 + j) * 64 + m];
            hb[j] = bf16_rne(v);
            lb[j] = bf16_rne(v - bf16_to_f32(hb[j]));
        }
        #pragma unroll
        for (int cp = 0; cp < 2; ++cp) {
            u16x8 vh, vl;
            #pragma unroll
            for (int j = 0; j < 8; ++j) { vh[j] = hb[cp * 8 + j]; vl[j] = lb[cp * 8 + j]; }
            int sidx = swz64(m, d0 + cp * 8);
            *reinterpret_cast<u16x8*>(&PJT_h[sidx]) = vh;
            *reinterpret_cast<u16x8*>(&PJT_l[sidx]) = vl;
        }
    }
    __syncthreads();

    f32x4 acc2[4] = {};
    float ksacc[4] = {0.f, 0.f, 0.f, 0.f};

    for (int sub = 0; sub < 4; ++sub) {
        const int rowL = chunk * 256 + sub * 64;   // global row

        float4 vv[4];
        {
            int l = t >> 2, c0 = (t & 3) << 4;
            #pragma unroll
            for (int k2 = 0; k2 < 4; ++k2)
                vv[k2] = *reinterpret_cast<const float4*>(
                    &kvb[(size_t)(rowL + l) * 2048 + 1024 + hh * 64 + c0 + k2 * 4]);
        }
        #pragma unroll
        for (int i = 0; i < 8; ++i) {
            int p = t + (i << 8);
            int l = p >> 5, i2 = p & 31;
            size_t base = (size_t)(rowL + l) * 2048 + hh * 64 + 2 * i2;
            float kr = kvb[base], ki = kvb[base + 1];
            int crow = (rowL + l) & 4095;
            float c = cosb[(size_t)crow * 32 + i2];
            float s = sinb[(size_t)crow * 32 + i2];
            float xr = kr * c - ki * s;
            float xi = kr * s + ki * c;
            unsigned short h0 = bf16_rne(xr), h1 = bf16_rne(xi);
            unsigned short l0 = bf16_rne(xr - bf16_to_f32(h0));
            unsigned short l1 = bf16_rne(xi - bf16_to_f32(h1));
            int sidx = swz64(l, 2 * i2);
            *reinterpret_cast<unsigned int*>(&KR_h[sidx]) = (unsigned)h0 | ((unsigned)h1 << 16);
            *reinterpret_cast<unsigned int*>(&KR_l[sidx]) = (unsigned)l0 | ((unsigned)l1 << 16);
        }
        if (t < 64) MS[t] = maskb[rowL + t];
        __syncthreads();   // B1

        f32x4 acc1[4] = {};
        #pragma unroll
        for (int ks = 0; ks < 2; ++ks) {
            bf16x8 ah = *reinterpret_cast<const bf16x8*>(&KR_h[swz64(16 * w + fr, ks * 32 + fq * 8)]);
            bf16x8 al = *reinterpret_cast<const bf16x8*>(&KR_l[swz64(16 * w + fr, ks * 32 + fq * 8)]);
            #pragma unroll
            for (int n = 0; n < 4; ++n) {
                bf16x8 bh = *reinterpret_cast<const bf16x8*>(&PJT_h[swz64(16 * n + fr, ks * 32 + fq * 8)]);
                bf16x8 bl = *reinterpret_cast<const bf16x8*>(&PJT_l[swz64(16 * n + fr, ks * 32 + fq * 8)]);
                acc1[n] = __builtin_amdgcn_mfma_f32_16x16x32_bf16(ah, bh, acc1[n], 0, 0, 0);
                acc1[n] = __builtin_amdgcn_mfma_f32_16x16x32_bf16(ah, bl, acc1[n], 0, 0, 0);
                acc1[n] = __builtin_amdgcn_mfma_f32_16x16x32_bf16(al, bh, acc1[n], 0, 0, 0);
            }
        }
        #pragma unroll
        for (int n = 0; n < 4; ++n) {
            unsigned short hb[4], lb[4];
            float ssum = 0.f;
            #pragma unroll
            for (int r = 0; r < 4; ++r) {
                int l = 16 * w + fq * 4 + r;
                float kp = fmaxf(acc1[n][r], 0.f) * MS[l];
                ssum += kp;
                hb[r] = bf16_rne(kp);
                lb[r] = bf16_rne(kp - bf16_to_f32(hb[r]));
            }
            ksacc[n] += ssum;
            int sidx = swz64(16 * n + fr, 16 * w + fq * 4);
            *reinterpret_cast<ushort4*>(&KPT_h[sidx]) = make_ushort4(hb[0], hb[1], hb[2], hb[3]);
            *reinterpret_cast<ushort4*>(&KPT_l[sidx]) = make_ushort4(lb[0], lb[1], lb[2], lb[3]);
        }
        __syncthreads();   // B2

        {
            float* VS = PS;
            int l = t >> 2, c0 = (t & 3) << 4;
            float mv = MS[l];
            #pragma unroll
            for (int k2 = 0; k2 < 4; ++k2) {
                float4 q = vv[k2];
                q.x *= mv; q.y *= mv; q.z *= mv; q.w *= mv;
                *reinterpret_cast<float4*>(&VS[l * 64 + c0 + k2 * 4]) = q;
            }
        }
        __syncthreads();   // B3

        {
            float* VS = PS;
            int d = t >> 2, l0 = (t & 3) << 4;
            unsigned short hb[16], lb[16];
            #pragma unroll
            for (int j = 0; j < 16; ++j) {
                float v = VS[(l0 + j) * 64 + d];
                hb[j] = bf16_rne(v);
                lb[j] = bf16_rne(v - bf16_to_f32(hb[j]));
            }
            #pragma unroll
            for (int cp = 0; cp < 2; ++cp) {
                u16x8 vh, vl;
                #pragma unroll
                for (int j = 0; j < 8; ++j) { vh[j] = hb[cp * 8 + j]; vl[j] = lb[cp * 8 + j]; }
                int sidx = swz64(d, l0 + cp * 8);
                *reinterpret_cast<u16x8*>(&VT_h[sidx]) = vh;
                *reinterpret_cast<u16x8*>(&VT_l[sidx]) = vl;
            }
        }
        __syncthreads();   // B4

        #pragma unroll
        for (int ks = 0; ks < 2; ++ks) {
            bf16x8 ah = *reinterpret_cast<const bf16x8*>(&KPT_h[swz64(16 * w + fr, ks * 32 + fq * 8)]);
            bf16x8 al = *reinterpret_cast<const bf16x8*>(&KPT_l[swz64(16 * w + fr, ks * 32 + fq * 8)]);
            #pragma unroll
            for (int n = 0; n < 4; ++n) {
                bf16x8 bh = *reinterpret_cast<const bf16x8*>(&VT_h[swz64(16 * n + fr, ks * 32 + fq * 8)]);
                bf16x8 bl = *reinterpret_cast<const bf16x8*>(&VT_l[swz64(16 * n + fr, ks * 32 + fq * 8)]);
                acc2[n] = __builtin_amdgcn_mfma_f32_16x16x32_bf16(ah, bh, acc2[n], 0, 0, 0);
                acc2[n] = __builtin_amdgcn_mfma_f32_16x16x32_bf16(ah, bl, acc2[n], 0, 0, 0);
                acc2[n] = __builtin_amdgcn_mfma_f32_16x16x32_bf16(al, bh, acc2[n], 0, 0, 0);
            }
        }
    }

    #pragma unroll
    for (int n = 0; n < 4; ++n) {
        float v = ksacc[n];
        v += __shfl_xor(v, 16);
        v += __shfl_xor(v, 32);
        if (fq == 0) KS[w * 64 + 16 * n + fr] = v;
    }
    __syncthreads();

    float* dst = partial + ((size_t)hh * 64 + chunk) * 4160;
    #pragma unroll
    for (int n = 0; n < 4; ++n)
        #pragma unroll
        for (int r = 0; r < 4; ++r) {
            int m = 16 * w + fq * 4 + r;
            int d = 16 * n + fr;
            dst[m * 64 + d] = acc2[n][r];
        }
    if (t < 64)
        dst[4096 + t] = KS[t] + KS[64 + t] + KS[128 + t] + KS[192 + t];
}

// Reduce 16 per-batch chunk partials -> kv (64x64) + ksum (64) per (b,h).
__global__ __launch_bounds__(256)
void kv_reduce_kernel(const float* __restrict__ partial, float* __restrict__ kvout)
{
    const int bh = blockIdx.x;          // b*16 + h
    const int b = bh >> 4, h = bh & 15;
    const int seg = blockIdx.y;         // 4160 = 4 segments x 1040
    for (int idx = seg * 1040 + threadIdx.x; idx < (seg + 1) * 1040; idx += 256) {
        float s = 0.f;
        for (int c = 0; c < 16; ++c)
            s += partial[((size_t)h * 64 + b * 16 + c) * 4160 + idx];
        kvout[(size_t)bh * 4160 + idx] = s;
    }
}

// ---------------------------------------------------------------------------
// context, full-batch (unchanged): grid (256, 16).
// ---------------------------------------------------------------------------
__global__ __launch_bounds__(256)
void context_kernel(const float* __restrict__ qb, const float* __restrict__ cosb,
                    const float* __restrict__ sinb, const float* __restrict__ proj,
                    const float* __restrict__ kvsum, unsigned short* __restrict__ ch,
                    unsigned short* __restrict__ cl)
{
    const int lt = blockIdx.x;   // 0..255
    const int h  = blockIdx.y;   // 0..15
    const int t = threadIdx.x;
    const int bh = (lt >> 6) * 16 + h;

    __shared__ float bufA[64][68];
    __shared__ float qp[64][68];
    __shared__ float pj[64][64];
    __shared__ float ksum[64];

    for (int i = t; i < 1024; i += 256)
        *reinterpret_cast<float4*>(&pj[0][0] + (size_t)i * 4) =
            *reinterpret_cast<const float4*>(proj + (size_t)h * 4096 + (size_t)i * 4);
    if (t < 64) ksum[t] = kvsum[(size_t)bh * 4160 + 4096 + t];

    const int rowL = lt * 64;            // global row
    #pragma unroll
    for (int i = 0; i < 8; ++i) {
        int p = t + i * 256;
        int l = p >> 5, i2 = p & 31;
        size_t base = (size_t)(rowL + l) * 1024 + h * HDIM + 2 * i2;
        float qr = qb[base], qi = qb[base + 1];
        int crow = (rowL + l) & 4095;
        float c = cosb[(size_t)crow * 32 + i2];
        float s = sinb[(size_t)crow * 32 + i2];
        bufA[l][2 * i2]     = qr * c - qi * s;
        bufA[l][2 * i2 + 1] = qr * s + qi * c;
    }
    __syncthreads();

    {
        int l = t >> 2, m0 = (t & 3) << 4;
        float a[16] = {};
        for (int d = 0; d < 64; ++d) {
            float ql = bufA[l][d];
            const float* pr = &pj[d][m0];
            #pragma unroll
            for (int j = 0; j < 16; ++j) a[j] = fmaf(ql, pr[j], a[j]);
        }
        #pragma unroll
        for (int j = 0; j < 16; ++j) qp[l][m0 + j] = fmaxf(a[j], 0.f);
    }
    __syncthreads();

    #pragma unroll
    for (int i = 0; i < 4; ++i) {
        int idx = t + i * 256;
        int mm = idx >> 4, dd = (idx & 15) << 2;
        *reinterpret_cast<float4*>(&bufA[mm][dd]) =
            *reinterpret_cast<const float4*>(&kvsum[(size_t)bh * 4160 + mm * 64 + dd]);
    }
    __syncthreads();

    {
        int l = t >> 2, d0 = (t & 3) << 4;
        float a[16] = {};
        float nrm = 0.f;
        for (int mm = 0; mm < 64; ++mm) {
            float qv = qp[l][mm];
            nrm = fmaf(qv, ksum[mm], nrm);
            const float* kr = &bufA[mm][d0];
            #pragma unroll
            for (int j = 0; j < 16; ++j) a[j] = fmaf(qv, kr[j], a[j]);
        }
        float inv = 1.0f / (nrm + 1e-4f);
        size_t orow = (size_t)(rowL + l) * 1024 + h * HDIM + d0;
        #pragma unroll
        for (int j4 = 0; j4 < 4; ++j4) {
            unsigned short hh2[4], ll2[4];
            #pragma unroll
            for (int j = 0; j < 4; ++j) {
                float v = a[j4 * 4 + j] * inv;
                hh2[j] = bf16_rne(v);
                ll2[j] = bf16_rne(v - bf16_to_f32(hh2[j]));
            }
            *reinterpret_cast<ushort4*>(&ch[orow + j4 * 4]) = make_ushort4(hh2[0], hh2[1], hh2[2], hh2[3]);
            *reinterpret_cast<ushort4*>(&cl[orow + j4 * 4]) = make_ushort4(ll2[0], ll2[1], ll2[2], ll2[3]);
        }
    }
}

extern "C" void kernel_launch(void* const* d_in, const int* in_sizes, int n_in,
                              void* d_out, int out_size, void* d_ws, size_t ws_size,
                              hipStream_t stream)
{
    const float* x    = (const float*)d_in[0];
    const float* fcos = (const float*)d_in[1];
    const float* fsin = (const float*)d_in[2];
    const float* mask = (const float*)d_in[3];
    const float* Wqkv = (const float*)d_in[4];
    const float* bqkv = (const float*)d_in[5];
    const float* proj = (const float*)d_in[6];
    const float* Wout = (const float*)d_in[7];
    const float* bout = (const float*)d_in[8];
    float* out = (float*)d_out;

    // Workspace (floats), 59,052,032 fl = 236.2 MB (< 256 MiB ws).
    float* W    = (float*)d_ws;          //  4,194,304 fl: weights hi/lo (transposed)
    float* XHL  = W + 4194304;           // 16,777,216 fl: x hi+lo bf16 -> later ctx hi+lo
    float* KVQ  = XHL + 16777216;        // 33,554,432 fl: KV fp32 [16384][2048] -> later Q [16384][1024]
    float* PART = KVQ + 33554432;        //  4,259,840 fl: partials [16][64][4160]
    float* KSUM = PART + 4259840;        //    266,240 fl: kvsum [64][4160]

    unsigned short* Wqh = (unsigned short*)W;       // Wqkv^T hi: [3072][1024]
    unsigned short* Wql = Wqh + 3145728;
    unsigned short* Woh = Wql + 3145728;            // Wout^T hi: [1024][1024]
    unsigned short* Wol = Woh + 1048576;
    unsigned short* xh  = (unsigned short*)XHL;     // also ctx hi (x dead by then)
    unsigned short* xl  = xh + 16777216;            // also ctx lo

    // Weight conversions (once per launch), transposed for B-operand K-contiguity
    convert_T_hilo<<<dim3(3072 / 64, 1024 / 64), 256, 0, stream>>>(Wqkv, Wqh, Wql, 1024, 3072);
    convert_T_hilo<<<dim3(1024 / 64, 1024 / 64), 256, 0, stream>>>(Wout, Woh, Wol, 1024, 1024);

    // x -> hi/lo, full batch
    convert_hilo<<<16384, 256, 0, stream>>>(x, xh, xl, ROWS * EMBED);

    // K,V = x @ Wqkv[:,1024:3072] + bqkv[1024:]  (full batch, [16384][2048])
    gemm3_kernel<<<dim3(2048 / 256, ROWS / 256), 512, 0, stream>>>(
        xh, xl, Wqh + (size_t)1024 * 1024, Wql + (size_t)1024 * 1024,
        bqkv + 1024, KVQ, 1024, 2048);

    // fused RoPE+proj+relu+mask -> kv partials (full batch)
    kv_mfma_kernel<<<dim3(64, 16), 256, 0, stream>>>(KVQ, fcos, fsin, mask, proj, PART);

    // reduce partials -> kv/ksum per (b,h)
    kv_reduce_kernel<<<dim3(64, 4), 256, 0, stream>>>(PART, KSUM);

    // Q = x @ Wqkv[:,0:1024] + bqkv[0:1024]  (overwrites KV region; KV dead)
    gemm3_kernel<<<dim3(1024 / 256, ROWS / 256), 512, 0, stream>>>(
        xh, xl, Wqh, Wql, bqkv, KVQ, 1024, 1024);

    // context + normalization; writes ctx hi/lo over xh/xl (x dead)
    context_kernel<<<dim3(256, 16), 256, 0, stream>>>(
        KVQ, fcos, fsin, proj, KSUM, xh, xl);

    // out = ctx @ Wout + bout
    gemm3_kernel<<<dim3(1024 / 256, ROWS / 256), 512, 0, stream>>>(
        xh, xl, Woh, Wol, bout, out, 1024, 1024);
}

// Round 15
// 500.640 us; speedup vs baseline: 1.1879x; 1.0048x over previous
//
#include <hip/hip_runtime.h>

#define LSEQ   4096
#define ROWS   16384             // 4 batches x 4096
#define EMBED  1024
#define NHEADS 16
#define HDIM   64
#define QKV_N  3072

typedef __attribute__((ext_vector_type(8))) short bf16x8;
typedef __attribute__((ext_vector_type(8))) unsigned short u16x8;
typedef __attribute__((ext_vector_type(4))) float f32x4;

// round-to-nearest-even fp32 -> bf16 (bit pattern), no header dependence
__device__ inline unsigned short bf16_rne(float x) {
    unsigned int u = __float_as_uint(x);
    unsigned int r = (u + 0x7fffu + ((u >> 16) & 1u)) >> 16;
    return (unsigned short)r;
}
__device__ inline float bf16_to_f32(unsigned short h) {
    return __uint_as_float(((unsigned int)h) << 16);
}

// swizzled short-index into a [64 rows][64 shorts] LDS tile (kv kernel)
__device__ __forceinline__ int swz64(int row, int s) {
    return row * 64 + ((((s >> 3) ^ (row & 7))) << 3) + (s & 7);
}

// ---------------------------------------------------------------------------
// Convert contiguous fp32 -> hi/lo bf16 arrays. n multiple of 1024.
// ---------------------------------------------------------------------------
__global__ __launch_bounds__(256)
void convert_hilo(const float* __restrict__ in, unsigned short* __restrict__ hi,
                  unsigned short* __restrict__ lo, int n)
{
    int i = (blockIdx.x * 256 + threadIdx.x) << 2;
    if (i >= n) return;
    float4 v = *reinterpret_cast<const float4*>(&in[i]);
    float a[4] = {v.x, v.y, v.z, v.w};
    unsigned short hh[4], ll[4];
    #pragma unroll
    for (int j = 0; j < 4; ++j) {
        hh[j] = bf16_rne(a[j]);
        ll[j] = bf16_rne(a[j] - bf16_to_f32(hh[j]));
    }
    *reinterpret_cast<ushort4*>(&hi[i]) = make_ushort4(hh[0], hh[1], hh[2], hh[3]);
    *reinterpret_cast<ushort4*>(&lo[i]) = make_ushort4(ll[0], ll[1], ll[2], ll[3]);
}

// ---------------------------------------------------------------------------
// Convert fp32 W[K][N] -> TRANSPOSED hi/lo bf16 Wt[N][K] (for B-operand).
// ---------------------------------------------------------------------------
__global__ __launch_bounds__(256)
void convert_T_hilo(const float* __restrict__ in, unsigned short* __restrict__ hi,
                    unsigned short* __restrict__ lo, int K, int N)
{
    __shared__ float tile[64][65];
    const int n0 = blockIdx.x * 64, k0 = blockIdx.y * 64;
    const int t = threadIdx.x;
    #pragma unroll
    for (int i = 0; i < 16; ++i) {
        int idx = t + i * 256;
        int r = idx >> 6, c = idx & 63;
        tile[r][c] = in[(size_t)(k0 + r) * N + n0 + c];
    }
    __syncthreads();
    #pragma unroll
    for (int i = 0; i < 16; ++i) {
        int idx = t + i * 256;
        int r = idx >> 6, c = idx & 63;
        float v = tile[c][r];
        unsigned short h = bf16_rne(v);
        unsigned short l = bf16_rne(v - bf16_to_f32(h));
        size_t o = (size_t)(n0 + r) * K + k0 + c;
        hi[o] = h;
        lo[o] = l;
    }
}

// ---------------------------------------------------------------------------
// bf16x3 split GEMM v11: counted-vmcnt pipeline (T4, m201/m218 mechanism).
// 256x256 block, 8 waves (2M x 4N), per-wave 128x64 = 8x4 frags of
// mfma_f32_16x16x32_bf16, BK=32, LDS 128 KB dbuf. v8's measured-zero-conflict
// swizzle unchanged.
// Staging roles: waves 0-3 stage A(h,l) 128-row halves with PHASE-ALIGNED
// issues (2 per phase; issue pair {2p,2p+1} = rows phase p of the NEXT tile
// reads) -> steady state: outstanding=8 at every phase end, oldest 2 = next
// phase's data -> uniform s_waitcnt vmcnt(6) (never 0). Waves 4-7 stage B:
// all 8 issues at p0, vmcnt(0) only at p3 (3 phases old, pre-satisfied).
// Last tile prefetches tile 0 (dummy, never read) to keep counts invariant.
// One barrier per phase; publish = stager's own vmcnt + barrier.
// M,N multiples of 256; K = 1024 (NT=32). Grid nwg % 8 == 0 (XCD swizzle).
// ---------------------------------------------------------------------------
__global__ __launch_bounds__(512)
void gemm3_kernel(const unsigned short* __restrict__ Ah, const unsigned short* __restrict__ Al,
                  const unsigned short* __restrict__ Bh, const unsigned short* __restrict__ Bl,
                  const float* __restrict__ bias, float* __restrict__ C,
                  int K, int ldc)
{
    __shared__ __align__(16) unsigned short lds[2][32768];   // 128 KB

    const int t = threadIdx.x;
    const int wave = t >> 6, lane = t & 63;
    const int wr = wave >> 2, wc = wave & 3;     // wave tile: 128 rows x 64 cols
    const int fr = lane & 15, fq = lane >> 4;

    // bijective XCD chunk swizzle (nwg % 8 == 0 for all our grids)
    const int nwg = gridDim.x * gridDim.y;
    const int wg  = blockIdx.y * gridDim.x + blockIdx.x;
    const int swz = (wg & 7) * (nwg >> 3) + (wg >> 3);
    const int bx = swz % gridDim.x, by = swz / gridDim.x;
    const int rowBase = by * 256;
    const int colBase = bx * 256;

    // staging: waves 0-1 Ah, 2-3 Al, 4-5 Bh, 6-7 Bl; each wave a 128-row half.
    const int op = wave >> 1;
    const bool isA = (wave < 4);
    const unsigned short* src = (op == 0) ? Ah : (op == 1) ? Al : (op == 2) ? Bh : Bl;
    const int tileRow0 = (isA ? rowBase : colBase) + (wave & 1) * 128;
    const int subOff = op * 8192 + (wave & 1) * 4096;            // shorts
    const int sRow = lane >> 2;                                  // 0..15
    const int sChunk = (((lane & 3) ^ ((lane >> 3) & 3)) << 3);  // swizzled k-chunk

    f32x4 acc[8][4] = {};
    const int NT = K >> 5;

    // prologue: stage tile 0 into buffer 0 (full drain once)
    #pragma unroll
    for (int i = 0; i < 8; ++i) {
        const unsigned short* g = src + (size_t)(tileRow0 + i * 16 + sRow) * K + sChunk;
        __builtin_amdgcn_global_load_lds(
            (const __attribute__((address_space(1))) void*)g,
            (__attribute__((address_space(3))) void*)&lds[0][subOff + i * 512], 16, 0, 0);
    }
    __syncthreads();

    for (int tI = 0; tI < NT; ++tI) {
        const int cur = tI & 1;
        const unsigned short* ldsC = lds[cur];
        // prefetch tile index (dummy tile-0 prefetch on last iter keeps vmcnt
        // invariants uniform; lands in buffer cur^1 which is never read again)
        const int kn = ((tI + 1 < NT) ? (tI + 1) : 0) << 5;

        bf16x8 bhf[4], blf[4];   // B fragments, register-resident across phases

        #pragma unroll
        for (int p = 0; p < 4; ++p) {
            // 1. ds_read this phase's A-frags (and all B-frags in phase 0);
            //    data published at previous phase's barrier.
            bf16x8 ahf[2], alf[2];
            #pragma unroll
            for (int mm = 0; mm < 2; ++mm) {
                int m = p * 2 + mm;
                int r = wr * 128 + m * 16 + fr;
                int off = r * 32 + ((fq ^ ((r >> 1) & 3)) << 3);
                ahf[mm] = *reinterpret_cast<const bf16x8*>(&ldsC[off]);
                alf[mm] = *reinterpret_cast<const bf16x8*>(&ldsC[8192 + off]);
            }
            if (p == 0) {
                #pragma unroll
                for (int n = 0; n < 4; ++n) {
                    int rb = wc * 64 + n * 16 + fr;
                    int off = rb * 32 + ((fq ^ ((rb >> 1) & 3)) << 3);
                    bhf[n] = *reinterpret_cast<const bf16x8*>(&ldsC[16384 + off]);
                    blf[n] = *reinterpret_cast<const bf16x8*>(&ldsC[24576 + off]);
                }
            }

            // 2. issue prefetch: A-stagers 2/phase (phase-aligned pairs);
            //    B-stagers all 8 at p0.
            if (isA) {
                #pragma unroll
                for (int i = 0; i < 2; ++i) {
                    const int ii = p * 2 + i;
                    const unsigned short* g =
                        src + (size_t)(tileRow0 + ii * 16 + sRow) * K + kn + sChunk;
                    __builtin_amdgcn_global_load_lds(
                        (const __attribute__((address_space(1))) void*)g,
                        (__attribute__((address_space(3))) void*)&lds[cur ^ 1][subOff + ii * 512], 16, 0, 0);
                }
            } else if (p == 0) {
                #pragma unroll
                for (int ii = 0; ii < 8; ++ii) {
                    const unsigned short* g =
                        src + (size_t)(tileRow0 + ii * 16 + sRow) * K + kn + sChunk;
                    __builtin_amdgcn_global_load_lds(
                        (const __attribute__((address_space(1))) void*)g,
                        (__attribute__((address_space(3))) void*)&lds[cur ^ 1][subOff + ii * 512], 16, 0, 0);
                }
            }

            // 3. counted waits (T4): A-stagers vmcnt(6) every phase;
            //    B-stagers full drain only at p3 (3 phases old).
            __builtin_amdgcn_sched_barrier(0);   // pin issues above the waitcnt
            if (isA) {
                asm volatile("s_waitcnt vmcnt(6) lgkmcnt(0)" ::: "memory");
            } else if (p == 3) {
                asm volatile("s_waitcnt vmcnt(0) lgkmcnt(0)" ::: "memory");
            } else {
                asm volatile("s_waitcnt lgkmcnt(0)" ::: "memory");
            }
            __builtin_amdgcn_s_barrier();        // publish
            __builtin_amdgcn_sched_barrier(0);   // rule #18 fence before MFMA

            // 4. MFMA cluster (T5)
            __builtin_amdgcn_s_setprio(1);
            #pragma unroll
            for (int mm = 0; mm < 2; ++mm) {
                int m = p * 2 + mm;
                #pragma unroll
                for (int n = 0; n < 4; ++n) {
                    acc[m][n] = __builtin_amdgcn_mfma_f32_16x16x32_bf16(ahf[mm], bhf[n], acc[m][n], 0, 0, 0);
                    acc[m][n] = __builtin_amdgcn_mfma_f32_16x16x32_bf16(ahf[mm], blf[n], acc[m][n], 0, 0, 0);
                    acc[m][n] = __builtin_amdgcn_mfma_f32_16x16x32_bf16(alf[mm], bhf[n], acc[m][n], 0, 0, 0);
                }
            }
            __builtin_amdgcn_s_setprio(0);
        }
    }

    // epilogue: C/D frag mapping col=lane&15, row=(lane>>4)*4+reg (m89-verified)
    #pragma unroll
    for (int m = 0; m < 8; ++m) {
        #pragma unroll
        for (int n = 0; n < 4; ++n) {
            int col = colBase + wc * 64 + n * 16 + fr;
            float bv = bias[col];
            #pragma unroll
            for (int r = 0; r < 4; ++r) {
                int row = rowBase + wr * 128 + m * 16 + fq * 4 + r;
                C[(size_t)row * ldc + col] = acc[m][n][r] + bv;
            }
        }
    }
}

// ---------------------------------------------------------------------------
// kv MFMA kernel, full-batch (unchanged): per (256-row chunk, head).
// ---------------------------------------------------------------------------
__global__ __launch_bounds__(256)
void kv_mfma_kernel(const float* __restrict__ kvb, const float* __restrict__ cosb,
                    const float* __restrict__ sinb, const float* __restrict__ maskb,
                    const float* __restrict__ proj, float* __restrict__ partial)
{
    __shared__ __align__(16) char smem[66816];
    unsigned short* KR_h  = (unsigned short*)smem;
    unsigned short* KR_l  = (unsigned short*)(smem + 8192);
    float*          PS    = (float*)smem;                    // aliases KR (fp32 [64][64])
    unsigned short* PJT_h = (unsigned short*)(smem + 16384);
    unsigned short* PJT_l = (unsigned short*)(smem + 24576);
    unsigned short* KPT_h = (unsigned short*)(smem + 32768);
    unsigned short* KPT_l = (unsigned short*)(smem + 40960);
    unsigned short* VT_h  = (unsigned short*)(smem + 49152);
    unsigned short* VT_l  = (unsigned short*)(smem + 57344);
    float*          MS    = (float*)(smem + 65536);
    float*          KS    = (float*)(smem + 65792);

    const int chunk = blockIdx.x;   // 0..63 (256 rows each)
    const int hh    = blockIdx.y;   // 0..15
    const int t = threadIdx.x;
    const int w = t >> 6, lane = t & 63;
    const int fr = lane & 15, fq = lane >> 4;

    {
        int r = t >> 2, c0 = (t & 3) << 4;
        #pragma unroll
        for (int k = 0; k < 4; ++k)
            *reinterpret_cast<float4*>(&PS[r * 64 + c0 + k * 4]) =
                *reinterpret_cast<const float4*>(&proj[(size_t)hh * 4096 + r * 64 + c0 + k * 4]);
    }
    __syncthreads();
    {
        int m = t >> 2, d0 = (t & 3) << 4;
        unsigned short hb[16], lb[16];
        #pragma unroll
        for (int j = 0; j < 16; ++j) {
            float v = PS[(d0 + j) * 64 + m];
            hb[j] = bf16_rne(v);
            lb[j] = bf16_rne(v - bf16_to_f32(hb[j]));
        }
        #pragma unroll
        for (int cp = 0; cp < 2; ++cp) {
            u16x8 vh, vl;
            #pragma unroll
            for (int j = 0; j < 8; ++j) { vh[j] = hb[cp * 8 + j]; vl[j] = lb[cp * 8 + j]; }
            int sidx = swz64(m, d0 + cp * 8);
            *reinterpret_cast<u16x8*>(&PJT_h[sidx]) = vh;
            *reinterpret_cast<u16x8*>(&PJT_l[sidx]) = vl;
        }
    }
    __syncthreads();

    f32x4 acc2[4] = {};
    float ksacc[4] = {0.f, 0.f, 0.f, 0.f};

    for (int sub = 0; sub < 4; ++sub) {
        const int rowL = chunk * 256 + sub * 64;   // global row

        float4 vv[4];
        {
            int l = t >> 2, c0 = (t & 3) << 4;
            #pragma unroll
            for (int k2 = 0; k2 < 4; ++k2)
                vv[k2] = *reinterpret_cast<const float4*>(
                    &kvb[(size_t)(rowL + l) * 2048 + 1024 + hh * 64 + c0 + k2 * 4]);
        }
        #pragma unroll
        for (int i = 0; i < 8; ++i) {
            int p = t + (i << 8);
            int l = p >> 5, i2 = p & 31;
            size_t base = (size_t)(rowL + l) * 2048 + hh * 64 + 2 * i2;
            float kr = kvb[base], ki = kvb[base + 1];
            int crow = (rowL + l) & 4095;
            float c = cosb[(size_t)crow * 32 + i2];
            float s = sinb[(size_t)crow * 32 + i2];
            float xr = kr * c - ki * s;
            float xi = kr * s + ki * c;
            unsigned short h0 = bf16_rne(xr), h1 = bf16_rne(xi);
            unsigned short l0 = bf16_rne(xr - bf16_to_f32(h0));
            unsigned short l1 = bf16_rne(xi - bf16_to_f32(h1));
            int sidx = swz64(l, 2 * i2);
            *reinterpret_cast<unsigned int*>(&KR_h[sidx]) = (unsigned)h0 | ((unsigned)h1 << 16);
            *reinterpret_cast<unsigned int*>(&KR_l[sidx]) = (unsigned)l0 | ((unsigned)l1 << 16);
        }
        if (t < 64) MS[t] = maskb[rowL + t];
        __syncthreads();   // B1

        f32x4 acc1[4] = {};
        #pragma unroll
        for (int ks = 0; ks < 2; ++ks) {
            bf16x8 ah = *reinterpret_cast<const bf16x8*>(&KR_h[swz64(16 * w + fr, ks * 32 + fq * 8)]);
            bf16x8 al = *reinterpret_cast<const bf16x8*>(&KR_l[swz64(16 * w + fr, ks * 32 + fq * 8)]);
            #pragma unroll
            for (int n = 0; n < 4; ++n) {
                bf16x8 bh = *reinterpret_cast<const bf16x8*>(&PJT_h[swz64(16 * n + fr, ks * 32 + fq * 8)]);
                bf16x8 bl = *reinterpret_cast<const bf16x8*>(&PJT_l[swz64(16 * n + fr, ks * 32 + fq * 8)]);
                acc1[n] = __builtin_amdgcn_mfma_f32_16x16x32_bf16(ah, bh, acc1[n], 0, 0, 0);
                acc1[n] = __builtin_amdgcn_mfma_f32_16x16x32_bf16(ah, bl, acc1[n], 0, 0, 0);
                acc1[n] = __builtin_amdgcn_mfma_f32_16x16x32_bf16(al, bh, acc1[n], 0, 0, 0);
            }
        }
        #pragma unroll
        for (int n = 0; n < 4; ++n) {
            unsigned short hb[4], lb[4];
            float ssum = 0.f;
            #pragma unroll
            for (int r = 0; r < 4; ++r) {
                int l = 16 * w + fq * 4 + r;
                float kp = fmaxf(acc1[n][r], 0.f) * MS[l];
                ssum += kp;
                hb[r] = bf16_rne(kp);
                lb[r] = bf16_rne(kp - bf16_to_f32(hb[r]));
            }
            ksacc[n] += ssum;
            int sidx = swz64(16 * n + fr, 16 * w + fq * 4);
            *reinterpret_cast<ushort4*>(&KPT_h[sidx]) = make_ushort4(hb[0], hb[1], hb[2], hb[3]);
            *reinterpret_cast<ushort4*>(&KPT_l[sidx]) = make_ushort4(lb[0], lb[1], lb[2], lb[3]);
        }
        __syncthreads();   // B2

        {
            float* VS = PS;
            int l = t >> 2, c0 = (t & 3) << 4;
            float mv = MS[l];
            #pragma unroll
            for (int k2 = 0; k2 < 4; ++k2) {
                float4 q = vv[k2];
                q.x *= mv; q.y *= mv; q.z *= mv; q.w *= mv;
                *reinterpret_cast<float4*>(&VS[l * 64 + c0 + k2 * 4]) = q;
            }
        }
        __syncthreads();   // B3

        {
            float* VS = PS;
            int d = t >> 2, l0 = (t & 3) << 4;
            unsigned short hb[16], lb[16];
            #pragma unroll
            for (int j = 0; j < 16; ++j) {
                float v = VS[(l0 + j) * 64 + d];
                hb[j] = bf16_rne(v);
                lb[j] = bf16_rne(v - bf16_to_f32(hb[j]));
            }
            #pragma unroll
            for (int cp = 0; cp < 2; ++cp) {
                u16x8 vh, vl;
                #pragma unroll
                for (int j = 0; j < 8; ++j) { vh[j] = hb[cp * 8 + j]; vl[j] = lb[cp * 8 + j]; }
                int sidx = swz64(d, l0 + cp * 8);
                *reinterpret_cast<u16x8*>(&VT_h[sidx]) = vh;
                *reinterpret_cast<u16x8*>(&VT_l[sidx]) = vl;
            }
        }
        __syncthreads();   // B4

        #pragma unroll
        for (int ks = 0; ks < 2; ++ks) {
            bf16x8 ah = *reinterpret_cast<const bf16x8*>(&KPT_h[swz64(16 * w + fr, ks * 32 + fq * 8)]);
            bf16x8 al = *reinterpret_cast<const bf16x8*>(&KPT_l[swz64(16 * w + fr, ks * 32 + fq * 8)]);
            #pragma unroll
            for (int n = 0; n < 4; ++n) {
                bf16x8 bh = *reinterpret_cast<const bf16x8*>(&VT_h[swz64(16 * n + fr, ks * 32 + fq * 8)]);
                bf16x8 bl = *reinterpret_cast<const bf16x8*>(&VT_l[swz64(16 * n + fr, ks * 32 + fq * 8)]);
                acc2[n] = __builtin_amdgcn_mfma_f32_16x16x32_bf16(ah, bh, acc2[n], 0, 0, 0);
                acc2[n] = __builtin_amdgcn_mfma_f32_16x16x32_bf16(ah, bl, acc2[n], 0, 0, 0);
                acc2[n] = __builtin_amdgcn_mfma_f32_16x16x32_bf16(al, bh, acc2[n], 0, 0, 0);
            }
        }
    }

    #pragma unroll
    for (int n = 0; n < 4; ++n) {
        float v = ksacc[n];
        v += __shfl_xor(v, 16);
        v += __shfl_xor(v, 32);
        if (fq == 0) KS[w * 64 + 16 * n + fr] = v;
    }
    __syncthreads();

    float* dst = partial + ((size_t)hh * 64 + chunk) * 4160;
    #pragma unroll
    for (int n = 0; n < 4; ++n)
        #pragma unroll
        for (int r = 0; r < 4; ++r) {
            int m = 16 * w + fq * 4 + r;
            int d = 16 * n + fr;
            dst[m * 64 + d] = acc2[n][r];
        }
    if (t < 64)
        dst[4096 + t] = KS[t] + KS[64 + t] + KS[128 + t] + KS[192 + t];
}

// Reduce 16 per-batch chunk partials -> kv (64x64) + ksum (64) per (b,h).
__global__ __launch_bounds__(256)
void kv_reduce_kernel(const float* __restrict__ partial, float* __restrict__ kvout)
{
    const int bh = blockIdx.x;          // b*16 + h
    const int b = bh >> 4, h = bh & 15;
    const int seg = blockIdx.y;         // 4160 = 4 segments x 1040
    for (int idx = seg * 1040 + threadIdx.x; idx < (seg + 1) * 1040; idx += 256) {
        float s = 0.f;
        for (int c = 0; c < 16; ++c)
            s += partial[((size_t)h * 64 + b * 16 + c) * 4160 + idx];
        kvout[(size_t)bh * 4160 + idx] = s;
    }
}

// ---------------------------------------------------------------------------
// context, full-batch (unchanged): grid (256, 16).
// ---------------------------------------------------------------------------
__global__ __launch_bounds__(256)
void context_kernel(const float* __restrict__ qb, const float* __restrict__ cosb,
                    const float* __restrict__ sinb, const float* __restrict__ proj,
                    const float* __restrict__ kvsum, unsigned short* __restrict__ ch,
                    unsigned short* __restrict__ cl)
{
    const int lt = blockIdx.x;   // 0..255
    const int h  = blockIdx.y;   // 0..15
    const int t = threadIdx.x;
    const int bh = (lt >> 6) * 16 + h;

    __shared__ float bufA[64][68];
    __shared__ float qp[64][68];
    __shared__ float pj[64][64];
    __shared__ float ksum[64];

    for (int i = t; i < 1024; i += 256)
        *reinterpret_cast<float4*>(&pj[0][0] + (size_t)i * 4) =
            *reinterpret_cast<const float4*>(proj + (size_t)h * 4096 + (size_t)i * 4);
    if (t < 64) ksum[t] = kvsum[(size_t)bh * 4160 + 4096 + t];

    const int rowL = lt * 64;            // global row
    #pragma unroll
    for (int i = 0; i < 8; ++i) {
        int p = t + i * 256;
        int l = p >> 5, i2 = p & 31;
        size_t base = (size_t)(rowL + l) * 1024 + h * HDIM + 2 * i2;
        float qr = qb[base], qi = qb[base + 1];
        int crow = (rowL + l) & 4095;
        float c = cosb[(size_t)crow * 32 + i2];
        float s = sinb[(size_t)crow * 32 + i2];
        bufA[l][2 * i2]     = qr * c - qi * s;
        bufA[l][2 * i2 + 1] = qr * s + qi * c;
    }
    __syncthreads();

    {
        int l = t >> 2, m0 = (t & 3) << 4;
        float a[16] = {};
        for (int d = 0; d < 64; ++d) {
            float ql = bufA[l][d];
            const float* pr = &pj[d][m0];
            #pragma unroll
            for (int j = 0; j < 16; ++j) a[j] = fmaf(ql, pr[j], a[j]);
        }
        #pragma unroll
        for (int j = 0; j < 16; ++j) qp[l][m0 + j] = fmaxf(a[j], 0.f);
    }
    __syncthreads();

    #pragma unroll
    for (int i = 0; i < 4; ++i) {
        int idx = t + i * 256;
        int mm = idx >> 4, dd = (idx & 15) << 2;
        *reinterpret_cast<float4*>(&bufA[mm][dd]) =
            *reinterpret_cast<const float4*>(&kvsum[(size_t)bh * 4160 + mm * 64 + dd]);
    }
    __syncthreads();

    {
        int l = t >> 2, d0 = (t & 3) << 4;
        float a[16] = {};
        float nrm = 0.f;
        for (int mm = 0; mm < 64; ++mm) {
            float qv = qp[l][mm];
            nrm = fmaf(qv, ksum[mm], nrm);
            const float* kr = &bufA[mm][d0];
            #pragma unroll
            for (int j = 0; j < 16; ++j) a[j] = fmaf(qv, kr[j], a[j]);
        }
        float inv = 1.0f / (nrm + 1e-4f);
        size_t orow = (size_t)(rowL + l) * 1024 + h * HDIM + d0;
        #pragma unroll
        for (int j4 = 0; j4 < 4; ++j4) {
            unsigned short hh2[4], ll2[4];
            #pragma unroll
            for (int j = 0; j < 4; ++j) {
                float v = a[j4 * 4 + j] * inv;
                hh2[j] = bf16_rne(v);
                ll2[j] = bf16_rne(v - bf16_to_f32(hh2[j]));
            }
            *reinterpret_cast<ushort4*>(&ch[orow + j4 * 4]) = make_ushort4(hh2[0], hh2[1], hh2[2], hh2[3]);
            *reinterpret_cast<ushort4*>(&cl[orow + j4 * 4]) = make_ushort4(ll2[0], ll2[1], ll2[2], ll2[3]);
        }
    }
}

extern "C" void kernel_launch(void* const* d_in, const int* in_sizes, int n_in,
                              void* d_out, int out_size, void* d_ws, size_t ws_size,
                              hipStream_t stream)
{
    const float* x    = (const float*)d_in[0];
    const float* fcos = (const float*)d_in[1];
    const float* fsin = (const float*)d_in[2];
    const float* mask = (const float*)d_in[3];
    const float* Wqkv = (const float*)d_in[4];
    const float* bqkv = (const float*)d_in[5];
    const float* proj = (const float*)d_in[6];
    const float* Wout = (const float*)d_in[7];
    const float* bout = (const float*)d_in[8];
    float* out = (float*)d_out;

    // Workspace (floats), 59,052,032 fl = 236.2 MB (< 256 MiB ws).
    float* W    = (float*)d_ws;          //  4,194,304 fl: weights hi/lo (transposed)
    float* XHL  = W + 4194304;           // 16,777,216 fl: x hi+lo bf16 -> later ctx hi+lo
    float* KVQ  = XHL + 16777216;        // 33,554,432 fl: KV fp32 [16384][2048] -> later Q [16384][1024]
    float* PART = KVQ + 33554432;        //  4,259,840 fl: partials [16][64][4160]
    float* KSUM = PART + 4259840;        //    266,240 fl: kvsum [64][4160]

    unsigned short* Wqh = (unsigned short*)W;       // Wqkv^T hi: [3072][1024]
    unsigned short* Wql = Wqh + 3145728;
    unsigned short* Woh = Wql + 3145728;            // Wout^T hi: [1024][1024]
    unsigned short* Wol = Woh + 1048576;
    unsigned short* xh  = (unsigned short*)XHL;     // also ctx hi (x dead by then)
    unsigned short* xl  = xh + 16777216;            // also ctx lo

    // Weight conversions (once per launch), transposed for B-operand K-contiguity
    convert_T_hilo<<<dim3(3072 / 64, 1024 / 64), 256, 0, stream>>>(Wqkv, Wqh, Wql, 1024, 3072);
    convert_T_hilo<<<dim3(1024 / 64, 1024 / 64), 256, 0, stream>>>(Wout, Woh, Wol, 1024, 1024);

    // x -> hi/lo, full batch
    convert_hilo<<<16384, 256, 0, stream>>>(x, xh, xl, ROWS * EMBED);

    // K,V = x @ Wqkv[:,1024:3072] + bqkv[1024:]  (full batch, [16384][2048])
    gemm3_kernel<<<dim3(2048 / 256, ROWS / 256), 512, 0, stream>>>(
        xh, xl, Wqh + (size_t)1024 * 1024, Wql + (size_t)1024 * 1024,
        bqkv + 1024, KVQ, 1024, 2048);

    // fused RoPE+proj+relu+mask -> kv partials (full batch)
    kv_mfma_kernel<<<dim3(64, 16), 256, 0, stream>>>(KVQ, fcos, fsin, mask, proj, PART);

    // reduce partials -> kv/ksum per (b,h)
    kv_reduce_kernel<<<dim3(64, 4), 256, 0, stream>>>(PART, KSUM);

    // Q = x @ Wqkv[:,0:1024] + bqkv[0:1024]  (overwrites KV region; KV dead)
    gemm3_kernel<<<dim3(1024 / 256, ROWS / 256), 512, 0, stream>>>(
        xh, xl, Wqh, Wql, bqkv, KVQ, 1024, 1024);

    // context + normalization; writes ctx hi/lo over xh/xl (x dead)
    context_kernel<<<dim3(256, 16), 256, 0, stream>>>(
        KVQ, fcos, fsin, proj, KSUM, xh, xl);

    // out = ctx @ Wout + bout
    gemm3_kernel<<<dim3(1024 / 256, ROWS / 256), 512, 0, stream>>>(
        xh, xl, Woh, Wol, bout, out, 1024, 1024);
}

// Round 16
// 498.986 us; speedup vs baseline: 1.1919x; 1.0033x over previous
//
#include <hip/hip_runtime.h>

#define LSEQ   4096
#define ROWS   16384             // 4 batches x 4096
#define EMBED  1024
#define NHEADS 16
#define HDIM   64
#define QKV_N  3072

typedef __attribute__((ext_vector_type(8))) short bf16x8;
typedef __attribute__((ext_vector_type(8))) unsigned short u16x8;
typedef __attribute__((ext_vector_type(4))) float f32x4;

// round-to-nearest-even fp32 -> bf16 (bit pattern), no header dependence
__device__ inline unsigned short bf16_rne(float x) {
    unsigned int u = __float_as_uint(x);
    unsigned int r = (u + 0x7fffu + ((u >> 16) & 1u)) >> 16;
    return (unsigned short)r;
}
__device__ inline float bf16_to_f32(unsigned short h) {
    return __uint_as_float(((unsigned int)h) << 16);
}

// swizzled short-index into a [64 rows][64 shorts] LDS tile (kv kernel)
__device__ __forceinline__ int swz64(int row, int s) {
    return row * 64 + ((((s >> 3) ^ (row & 7))) << 3) + (s & 7);
}

// ---------------------------------------------------------------------------
// Convert contiguous fp32 -> hi/lo bf16 arrays. n multiple of 1024.
// ---------------------------------------------------------------------------
__global__ __launch_bounds__(256)
void convert_hilo(const float* __restrict__ in, unsigned short* __restrict__ hi,
                  unsigned short* __restrict__ lo, int n)
{
    int i = (blockIdx.x * 256 + threadIdx.x) << 2;
    if (i >= n) return;
    float4 v = *reinterpret_cast<const float4*>(&in[i]);
    float a[4] = {v.x, v.y, v.z, v.w};
    unsigned short hh[4], ll[4];
    #pragma unroll
    for (int j = 0; j < 4; ++j) {
        hh[j] = bf16_rne(a[j]);
        ll[j] = bf16_rne(a[j] - bf16_to_f32(hh[j]));
    }
    *reinterpret_cast<ushort4*>(&hi[i]) = make_ushort4(hh[0], hh[1], hh[2], hh[3]);
    *reinterpret_cast<ushort4*>(&lo[i]) = make_ushort4(ll[0], ll[1], ll[2], ll[3]);
}

// ---------------------------------------------------------------------------
// Convert fp32 W[K][N] -> TRANSPOSED hi/lo bf16 Wt[N][K] (for B-operand).
// ---------------------------------------------------------------------------
__global__ __launch_bounds__(256)
void convert_T_hilo(const float* __restrict__ in, unsigned short* __restrict__ hi,
                    unsigned short* __restrict__ lo, int K, int N)
{
    __shared__ float tile[64][65];
    const int n0 = blockIdx.x * 64, k0 = blockIdx.y * 64;
    const int t = threadIdx.x;
    #pragma unroll
    for (int i = 0; i < 16; ++i) {
        int idx = t + i * 256;
        int r = idx >> 6, c = idx & 63;
        tile[r][c] = in[(size_t)(k0 + r) * N + n0 + c];
    }
    __syncthreads();
    #pragma unroll
    for (int i = 0; i < 16; ++i) {
        int idx = t + i * 256;
        int r = idx >> 6, c = idx & 63;
        float v = tile[c][r];
        unsigned short h = bf16_rne(v);
        unsigned short l = bf16_rne(v - bf16_to_f32(h));
        size_t o = (size_t)(n0 + r) * K + k0 + c;
        hi[o] = h;
        lo[o] = l;
    }
}

// ---------------------------------------------------------------------------
// bf16x3 split GEMM v12: intra-tile register pipeline.
// Diagnosis (R13-R15): all phase-barrier schedules serialize the LDS pipe and
// the MFMA pipe (measured K-tile time = their SUM; MfmaUtil pinned ~50%),
// because each phase issues reads then immediately lgkmcnt(0)s them, and no
// LDS work is in flight during the MFMA cluster.
// Fix: ONE barrier per K-tile (__syncthreads; its vmcnt drain is pre-satisfied
// ~3700 cy after the up-front staging issues). Within the tile: read B-frags +
// A-phase-0, then for p=0..3 { read A[p+1] (plain loads, compiler emits
// counted lgkmcnt) ; MFMA phase p } -> the p+1 reads run on the LDS pipe
// UNDER phase p's MFMAs. A-frag regs ping-pong with compile-time indices.
// 256x256 block, 8 waves (2M x 4N), BK=32, LDS 128 KB dbuf, v8's measured-
// zero-conflict swizzle, XCD chunk swizzle (nwg % 8 == 0).
// ---------------------------------------------------------------------------
__global__ __launch_bounds__(512)
void gemm3_kernel(const unsigned short* __restrict__ Ah, const unsigned short* __restrict__ Al,
                  const unsigned short* __restrict__ Bh, const unsigned short* __restrict__ Bl,
                  const float* __restrict__ bias, float* __restrict__ C,
                  int K, int ldc)
{
    __shared__ __align__(16) unsigned short lds[2][32768];   // 128 KB

    const int t = threadIdx.x;
    const int wave = t >> 6, lane = t & 63;
    const int wr = wave >> 2, wc = wave & 3;     // wave tile: 128 rows x 64 cols
    const int fr = lane & 15, fq = lane >> 4;

    // bijective XCD chunk swizzle (nwg % 8 == 0 for all our grids)
    const int nwg = gridDim.x * gridDim.y;
    const int wg  = blockIdx.y * gridDim.x + blockIdx.x;
    const int swz = (wg & 7) * (nwg >> 3) + (wg >> 3);
    const int bx = swz % gridDim.x, by = swz / gridDim.x;
    const int rowBase = by * 256;
    const int colBase = bx * 256;

    // staging: waves 0-1 Ah, 2-3 Al, 4-5 Bh, 6-7 Bl; each wave a 128-row half.
    const int op = wave >> 1;
    const unsigned short* src = (op == 0) ? Ah : (op == 1) ? Al : (op == 2) ? Bh : Bl;
    const int tileRow0 = ((wave < 4) ? rowBase : colBase) + (wave & 1) * 128;
    const int subOff = op * 8192 + (wave & 1) * 4096;            // shorts
    const int sRow = lane >> 2;                                  // 0..15
    const int sChunk = (((lane & 3) ^ ((lane >> 3) & 3)) << 3);  // swizzled k-chunk

    f32x4 acc[8][4] = {};
    const int NT = K >> 5;

    // prologue: stage tile 0 into buffer 0 (full drain once)
    #pragma unroll
    for (int i = 0; i < 8; ++i) {
        const unsigned short* g = src + (size_t)(tileRow0 + i * 16 + sRow) * K + sChunk;
        __builtin_amdgcn_global_load_lds(
            (const __attribute__((address_space(1))) void*)g,
            (__attribute__((address_space(3))) void*)&lds[0][subOff + i * 512], 16, 0, 0);
    }
    __syncthreads();

    for (int tI = 0; tI < NT; ++tI) {
        const int cur = tI & 1;
        const unsigned short* ldsC = lds[cur];
        // dummy tile-0 prefetch on last iter keeps code uniform (never read)
        const int kn = ((tI + 1 < NT) ? (tI + 1) : 0) << 5;

        // issue ALL staging for next tile up front; the tile-end __syncthreads
        // drains it ~3700 cy later (pre-satisfied).
        #pragma unroll
        for (int i = 0; i < 8; ++i) {
            const unsigned short* g =
                src + (size_t)(tileRow0 + i * 16 + sRow) * K + kn + sChunk;
            __builtin_amdgcn_global_load_lds(
                (const __attribute__((address_space(1))) void*)g,
                (__attribute__((address_space(3))) void*)&lds[cur ^ 1][subOff + i * 512], 16, 0, 0);
        }

        // B fragments (whole tile) + A fragments phase 0
        bf16x8 bhf[4], blf[4];
        #pragma unroll
        for (int n = 0; n < 4; ++n) {
            int rb = wc * 64 + n * 16 + fr;
            int off = rb * 32 + ((fq ^ ((rb >> 1) & 3)) << 3);
            bhf[n] = *reinterpret_cast<const bf16x8*>(&ldsC[16384 + off]);
            blf[n] = *reinterpret_cast<const bf16x8*>(&ldsC[24576 + off]);
        }
        bf16x8 ahf[2][2], alf[2][2];   // ping-pong, all indices compile-time
        #pragma unroll
        for (int mm = 0; mm < 2; ++mm) {
            int r = wr * 128 + mm * 16 + fr;
            int off = r * 32 + ((fq ^ ((r >> 1) & 3)) << 3);
            ahf[0][mm] = *reinterpret_cast<const bf16x8*>(&ldsC[off]);
            alf[0][mm] = *reinterpret_cast<const bf16x8*>(&ldsC[8192 + off]);
        }

        #pragma unroll
        for (int p = 0; p < 4; ++p) {
            const int cb = p & 1, nb = cb ^ 1;
            // prefetch next phase's A-frags; these ds_reads execute on the LDS
            // pipe while this phase's MFMAs run (compiler emits counted lgkmcnt)
            if (p < 3) {
                #pragma unroll
                for (int mm = 0; mm < 2; ++mm) {
                    int m = (p + 1) * 2 + mm;
                    int r = wr * 128 + m * 16 + fr;
                    int off = r * 32 + ((fq ^ ((r >> 1) & 3)) << 3);
                    ahf[nb][mm] = *reinterpret_cast<const bf16x8*>(&ldsC[off]);
                    alf[nb][mm] = *reinterpret_cast<const bf16x8*>(&ldsC[8192 + off]);
                }
            }
            __builtin_amdgcn_s_setprio(1);
            #pragma unroll
            for (int mm = 0; mm < 2; ++mm) {
                int m = p * 2 + mm;
                #pragma unroll
                for (int n = 0; n < 4; ++n) {
                    acc[m][n] = __builtin_amdgcn_mfma_f32_16x16x32_bf16(ahf[cb][mm], bhf[n], acc[m][n], 0, 0, 0);
                    acc[m][n] = __builtin_amdgcn_mfma_f32_16x16x32_bf16(ahf[cb][mm], blf[n], acc[m][n], 0, 0, 0);
                    acc[m][n] = __builtin_amdgcn_mfma_f32_16x16x32_bf16(alf[cb][mm], bhf[n], acc[m][n], 0, 0, 0);
                }
            }
            __builtin_amdgcn_s_setprio(0);
        }

        __syncthreads();   // publish staged tile; vmcnt/lgkm drains pre-satisfied
    }

    // epilogue: C/D frag mapping col=lane&15, row=(lane>>4)*4+reg (m89-verified)
    #pragma unroll
    for (int m = 0; m < 8; ++m) {
        #pragma unroll
        for (int n = 0; n < 4; ++n) {
            int col = colBase + wc * 64 + n * 16 + fr;
            float bv = bias[col];
            #pragma unroll
            for (int r = 0; r < 4; ++r) {
                int row = rowBase + wr * 128 + m * 16 + fq * 4 + r;
                C[(size_t)row * ldc + col] = acc[m][n][r] + bv;
            }
        }
    }
}

// ---------------------------------------------------------------------------
// kv MFMA kernel, full-batch (unchanged): per (256-row chunk, head).
// ---------------------------------------------------------------------------
__global__ __launch_bounds__(256)
void kv_mfma_kernel(const float* __restrict__ kvb, const float* __restrict__ cosb,
                    const float* __restrict__ sinb, const float* __restrict__ maskb,
                    const float* __restrict__ proj, float* __restrict__ partial)
{
    __shared__ __align__(16) char smem[66816];
    unsigned short* KR_h  = (unsigned short*)smem;
    unsigned short* KR_l  = (unsigned short*)(smem + 8192);
    float*          PS    = (float*)smem;                    // aliases KR (fp32 [64][64])
    unsigned short* PJT_h = (unsigned short*)(smem + 16384);
    unsigned short* PJT_l = (unsigned short*)(smem + 24576);
    unsigned short* KPT_h = (unsigned short*)(smem + 32768);
    unsigned short* KPT_l = (unsigned short*)(smem + 40960);
    unsigned short* VT_h  = (unsigned short*)(smem + 49152);
    unsigned short* VT_l  = (unsigned short*)(smem + 57344);
    float*          MS    = (float*)(smem + 65536);
    float*          KS    = (float*)(smem + 65792);

    const int chunk = blockIdx.x;   // 0..63 (256 rows each)
    const int hh    = blockIdx.y;   // 0..15
    const int t = threadIdx.x;
    const int w = t >> 6, lane = t & 63;
    const int fr = lane & 15, fq = lane >> 4;

    {
        int r = t >> 2, c0 = (t & 3) << 4;
        #pragma unroll
        for (int k = 0; k < 4; ++k)
            *reinterpret_cast<float4*>(&PS[r * 64 + c0 + k * 4]) =
                *reinterpret_cast<const float4*>(&proj[(size_t)hh * 4096 + r * 64 + c0 + k * 4]);
    }
    __syncthreads();
    {
        int m = t >> 2, d0 = (t & 3) << 4;
        unsigned short hb[16], lb[16];
        #pragma unroll
        for (int j = 0; j < 16; ++j) {
            float v = PS[(d0 + j) * 64 + m];
            hb[j] = bf16_rne(v);
            lb[j] = bf16_rne(v - bf16_to_f32(hb[j]));
        }
        #pragma unroll
        for (int cp = 0; cp < 2; ++cp) {
            u16x8 vh, vl;
            #pragma unroll
            for (int j = 0; j < 8; ++j) { vh[j] = hb[cp * 8 + j]; vl[j] = lb[cp * 8 + j]; }
            int sidx = swz64(m, d0 + cp * 8);
            *reinterpret_cast<u16x8*>(&PJT_h[sidx]) = vh;
            *reinterpret_cast<u16x8*>(&PJT_l[sidx]) = vl;
        }
    }
    __syncthreads();

    f32x4 acc2[4] = {};
    float ksacc[4] = {0.f, 0.f, 0.f, 0.f};

    for (int sub = 0; sub < 4; ++sub) {
        const int rowL = chunk * 256 + sub * 64;   // global row

        float4 vv[4];
        {
            int l = t >> 2, c0 = (t & 3) << 4;
            #pragma unroll
            for (int k2 = 0; k2 < 4; ++k2)
                vv[k2] = *reinterpret_cast<const float4*>(
                    &kvb[(size_t)(rowL + l) * 2048 + 1024 + hh * 64 + c0 + k2 * 4]);
        }
        #pragma unroll
        for (int i = 0; i < 8; ++i) {
            int p = t + (i << 8);
            int l = p >> 5, i2 = p & 31;
            size_t base = (size_t)(rowL + l) * 2048 + hh * 64 + 2 * i2;
            float kr = kvb[base], ki = kvb[base + 1];
            int crow = (rowL + l) & 4095;
            float c = cosb[(size_t)crow * 32 + i2];
            float s = sinb[(size_t)crow * 32 + i2];
            float xr = kr * c - ki * s;
            float xi = kr * s + ki * c;
            unsigned short h0 = bf16_rne(xr), h1 = bf16_rne(xi);
            unsigned short l0 = bf16_rne(xr - bf16_to_f32(h0));
            unsigned short l1 = bf16_rne(xi - bf16_to_f32(h1));
            int sidx = swz64(l, 2 * i2);
            *reinterpret_cast<unsigned int*>(&KR_h[sidx]) = (unsigned)h0 | ((unsigned)h1 << 16);
            *reinterpret_cast<unsigned int*>(&KR_l[sidx]) = (unsigned)l0 | ((unsigned)l1 << 16);
        }
        if (t < 64) MS[t] = maskb[rowL + t];
        __syncthreads();   // B1

        f32x4 acc1[4] = {};
        #pragma unroll
        for (int ks = 0; ks < 2; ++ks) {
            bf16x8 ah = *reinterpret_cast<const bf16x8*>(&KR_h[swz64(16 * w + fr, ks * 32 + fq * 8)]);
            bf16x8 al = *reinterpret_cast<const bf16x8*>(&KR_l[swz64(16 * w + fr, ks * 32 + fq * 8)]);
            #pragma unroll
            for (int n = 0; n < 4; ++n) {
                bf16x8 bh = *reinterpret_cast<const bf16x8*>(&PJT_h[swz64(16 * n + fr, ks * 32 + fq * 8)]);
                bf16x8 bl = *reinterpret_cast<const bf16x8*>(&PJT_l[swz64(16 * n + fr, ks * 32 + fq * 8)]);
                acc1[n] = __builtin_amdgcn_mfma_f32_16x16x32_bf16(ah, bh, acc1[n], 0, 0, 0);
                acc1[n] = __builtin_amdgcn_mfma_f32_16x16x32_bf16(ah, bl, acc1[n], 0, 0, 0);
                acc1[n] = __builtin_amdgcn_mfma_f32_16x16x32_bf16(al, bh, acc1[n], 0, 0, 0);
            }
        }
        #pragma unroll
        for (int n = 0; n < 4; ++n) {
            unsigned short hb[4], lb[4];
            float ssum = 0.f;
            #pragma unroll
            for (int r = 0; r < 4; ++r) {
                int l = 16 * w + fq * 4 + r;
                float kp = fmaxf(acc1[n][r], 0.f) * MS[l];
                ssum += kp;
                hb[r] = bf16_rne(kp);
                lb[r] = bf16_rne(kp - bf16_to_f32(hb[r]));
            }
            ksacc[n] += ssum;
            int sidx = swz64(16 * n + fr, 16 * w + fq * 4);
            *reinterpret_cast<ushort4*>(&KPT_h[sidx]) = make_ushort4(hb[0], hb[1], hb[2], hb[3]);
            *reinterpret_cast<ushort4*>(&KPT_l[sidx]) = make_ushort4(lb[0], lb[1], lb[2], lb[3]);
        }
        __syncthreads();   // B2

        {
            float* VS = PS;
            int l = t >> 2, c0 = (t & 3) << 4;
            float mv = MS[l];
            #pragma unroll
            for (int k2 = 0; k2 < 4; ++k2) {
                float4 q = vv[k2];
                q.x *= mv; q.y *= mv; q.z *= mv; q.w *= mv;
                *reinterpret_cast<float4*>(&VS[l * 64 + c0 + k2 * 4]) = q;
            }
        }
        __syncthreads();   // B3

        {
            float* VS = PS;
            int d = t >> 2, l0 = (t & 3) << 4;
            unsigned short hb[16], lb[16];
            #pragma unroll
            for (int j = 0; j < 16; ++j) {
                float v = VS[(l0 + j) * 64 + d];
                hb[j] = bf16_rne(v);
                lb[j] = bf16_rne(v - bf16_to_f32(hb[j]));
            }
            #pragma unroll
            for (int cp = 0; cp < 2; ++cp) {
                u16x8 vh, vl;
                #pragma unroll
                for (int j = 0; j < 8; ++j) { vh[j] = hb[cp * 8 + j]; vl[j] = lb[cp * 8 + j]; }
                int sidx = swz64(d, l0 + cp * 8);
                *reinterpret_cast<u16x8*>(&VT_h[sidx]) = vh;
                *reinterpret_cast<u16x8*>(&VT_l[sidx]) = vl;
            }
        }
        __syncthreads();   // B4

        #pragma unroll
        for (int ks = 0; ks < 2; ++ks) {
            bf16x8 ah = *reinterpret_cast<const bf16x8*>(&KPT_h[swz64(16 * w + fr, ks * 32 + fq * 8)]);
            bf16x8 al = *reinterpret_cast<const bf16x8*>(&KPT_l[swz64(16 * w + fr, ks * 32 + fq * 8)]);
            #pragma unroll
            for (int n = 0; n < 4; ++n) {
                bf16x8 bh = *reinterpret_cast<const bf16x8*>(&VT_h[swz64(16 * n + fr, ks * 32 + fq * 8)]);
                bf16x8 bl = *reinterpret_cast<const bf16x8*>(&VT_l[swz64(16 * n + fr, ks * 32 + fq * 8)]);
                acc2[n] = __builtin_amdgcn_mfma_f32_16x16x32_bf16(ah, bh, acc2[n], 0, 0, 0);
                acc2[n] = __builtin_amdgcn_mfma_f32_16x16x32_bf16(ah, bl, acc2[n], 0, 0, 0);
                acc2[n] = __builtin_amdgcn_mfma_f32_16x16x32_bf16(al, bh, acc2[n], 0, 0, 0);
            }
        }
    }

    #pragma unroll
    for (int n = 0; n < 4; ++n) {
        float v = ksacc[n];
        v += __shfl_xor(v, 16);
        v += __shfl_xor(v, 32);
        if (fq == 0) KS[w * 64 + 16 * n + fr] = v;
    }
    __syncthreads();

    float* dst = partial + ((size_t)hh * 64 + chunk) * 4160;
    #pragma unroll
    for (int n = 0; n < 4; ++n)
        #pragma unroll
        for (int r = 0; r < 4; ++r) {
            int m = 16 * w + fq * 4 + r;
            int d = 16 * n + fr;
            dst[m * 64 + d] = acc2[n][r];
        }
    if (t < 64)
        dst[4096 + t] = KS[t] + KS[64 + t] + KS[128 + t] + KS[192 + t];
}

// Reduce 16 per-batch chunk partials -> kv (64x64) + ksum (64) per (b,h).
__global__ __launch_bounds__(256)
void kv_reduce_kernel(const float* __restrict__ partial, float* __restrict__ kvout)
{
    const int bh = blockIdx.x;          // b*16 + h
    const int b = bh >> 4, h = bh & 15;
    const int seg = blockIdx.y;         // 4160 = 4 segments x 1040
    for (int idx = seg * 1040 + threadIdx.x; idx < (seg + 1) * 1040; idx += 256) {
        float s = 0.f;
        for (int c = 0; c < 16; ++c)
            s += partial[((size_t)h * 64 + b * 16 + c) * 4160 + idx];
        kvout[(size_t)bh * 4160 + idx] = s;
    }
}

// ---------------------------------------------------------------------------
// context, full-batch (unchanged): grid (256, 16).
// ---------------------------------------------------------------------------
__global__ __launch_bounds__(256)
void context_kernel(const float* __restrict__ qb, const float* __restrict__ cosb,
                    const float* __restrict__ sinb, const float* __restrict__ proj,
                    const float* __restrict__ kvsum, unsigned short* __restrict__ ch,
                    unsigned short* __restrict__ cl)
{
    const int lt = blockIdx.x;   // 0..255
    const int h  = blockIdx.y;   // 0..15
    const int t = threadIdx.x;
    const int bh = (lt >> 6) * 16 + h;

    __shared__ float bufA[64][68];
    __shared__ float qp[64][68];
    __shared__ float pj[64][64];
    __shared__ float ksum[64];

    for (int i = t; i < 1024; i += 256)
        *reinterpret_cast<float4*>(&pj[0][0] + (size_t)i * 4) =
            *reinterpret_cast<const float4*>(proj + (size_t)h * 4096 + (size_t)i * 4);
    if (t < 64) ksum[t] = kvsum[(size_t)bh * 4160 + 4096 + t];

    const int rowL = lt * 64;            // global row
    #pragma unroll
    for (int i = 0; i < 8; ++i) {
        int p = t + i * 256;
        int l = p >> 5, i2 = p & 31;
        size_t base = (size_t)(rowL + l) * 1024 + h * HDIM + 2 * i2;
        float qr = qb[base], qi = qb[base + 1];
        int crow = (rowL + l) & 4095;
        float c = cosb[(size_t)crow * 32 + i2];
        float s = sinb[(size_t)crow * 32 + i2];
        bufA[l][2 * i2]     = qr * c - qi * s;
        bufA[l][2 * i2 + 1] = qr * s + qi * c;
    }
    __syncthreads();

    {
        int l = t >> 2, m0 = (t & 3) << 4;
        float a[16] = {};
        for (int d = 0; d < 64; ++d) {
            float ql = bufA[l][d];
            const float* pr = &pj[d][m0];
            #pragma unroll
            for (int j = 0; j < 16; ++j) a[j] = fmaf(ql, pr[j], a[j]);
        }
        #pragma unroll
        for (int j = 0; j < 16; ++j) qp[l][m0 + j] = fmaxf(a[j], 0.f);
    }
    __syncthreads();

    #pragma unroll
    for (int i = 0; i < 4; ++i) {
        int idx = t + i * 256;
        int mm = idx >> 4, dd = (idx & 15) << 2;
        *reinterpret_cast<float4*>(&bufA[mm][dd]) =
            *reinterpret_cast<const float4*>(&kvsum[(size_t)bh * 4160 + mm * 64 + dd]);
    }
    __syncthreads();

    {
        int l = t >> 2, d0 = (t & 3) << 4;
        float a[16] = {};
        float nrm = 0.f;
        for (int mm = 0; mm < 64; ++mm) {
            float qv = qp[l][mm];
            nrm = fmaf(qv, ksum[mm], nrm);
            const float* kr = &bufA[mm][d0];
            #pragma unroll
            for (int j = 0; j < 16; ++j) a[j] = fmaf(qv, kr[j], a[j]);
        }
        float inv = 1.0f / (nrm + 1e-4f);
        size_t orow = (size_t)(rowL + l) * 1024 + h * HDIM + d0;
        #pragma unroll
        for (int j4 = 0; j4 < 4; ++j4) {
            unsigned short hh2[4], ll2[4];
            #pragma unroll
            for (int j = 0; j < 4; ++j) {
                float v = a[j4 * 4 + j] * inv;
                hh2[j] = bf16_rne(v);
                ll2[j] = bf16_rne(v - bf16_to_f32(hh2[j]));
            }
            *reinterpret_cast<ushort4*>(&ch[orow + j4 * 4]) = make_ushort4(hh2[0], hh2[1], hh2[2], hh2[3]);
            *reinterpret_cast<ushort4*>(&cl[orow + j4 * 4]) = make_ushort4(ll2[0], ll2[1], ll2[2], ll2[3]);
        }
    }
}

extern "C" void kernel_launch(void* const* d_in, const int* in_sizes, int n_in,
                              void* d_out, int out_size, void* d_ws, size_t ws_size,
                              hipStream_t stream)
{
    const float* x    = (const float*)d_in[0];
    const float* fcos = (const float*)d_in[1];
    const float* fsin = (const float*)d_in[2];
    const float* mask = (const float*)d_in[3];
    const float* Wqkv = (const float*)d_in[4];
    const float* bqkv = (const float*)d_in[5];
    const float* proj = (const float*)d_in[6];
    const float* Wout = (const float*)d_in[7];
    const float* bout = (const float*)d_in[8];
    float* out = (float*)d_out;

    // Workspace (floats), 59,052,032 fl = 236.2 MB (< 256 MiB ws).
    float* W    = (float*)d_ws;          //  4,194,304 fl: weights hi/lo (transposed)
    float* XHL  = W + 4194304;           // 16,777,216 fl: x hi+lo bf16 -> later ctx hi+lo
    float* KVQ  = XHL + 16777216;        // 33,554,432 fl: KV fp32 [16384][2048] -> later Q [16384][1024]
    float* PART = KVQ + 33554432;        //  4,259,840 fl: partials [16][64][4160]
    float* KSUM = PART + 4259840;        //    266,240 fl: kvsum [64][4160]

    unsigned short* Wqh = (unsigned short*)W;       // Wqkv^T hi: [3072][1024]
    unsigned short* Wql = Wqh + 3145728;
    unsigned short* Woh = Wql + 3145728;            // Wout^T hi: [1024][1024]
    unsigned short* Wol = Woh + 1048576;
    unsigned short* xh  = (unsigned short*)XHL;     // also ctx hi (x dead by then)
    unsigned short* xl  = xh + 16777216;            // also ctx lo

    // Weight conversions (once per launch), transposed for B-operand K-contiguity
    convert_T_hilo<<<dim3(3072 / 64, 1024 / 64), 256, 0, stream>>>(Wqkv, Wqh, Wql, 1024, 3072);
    convert_T_hilo<<<dim3(1024 / 64, 1024 / 64), 256, 0, stream>>>(Wout, Woh, Wol, 1024, 1024);

    // x -> hi/lo, full batch
    convert_hilo<<<16384, 256, 0, stream>>>(x, xh, xl, ROWS * EMBED);

    // K,V = x @ Wqkv[:,1024:3072] + bqkv[1024:]  (full batch, [16384][2048])
    gemm3_kernel<<<dim3(2048 / 256, ROWS / 256), 512, 0, stream>>>(
        xh, xl, Wqh + (size_t)1024 * 1024, Wql + (size_t)1024 * 1024,
        bqkv + 1024, KVQ, 1024, 2048);

    // fused RoPE+proj+relu+mask -> kv partials (full batch)
    kv_mfma_kernel<<<dim3(64, 16), 256, 0, stream>>>(KVQ, fcos, fsin, mask, proj, PART);

    // reduce partials -> kv/ksum per (b,h)
    kv_reduce_kernel<<<dim3(64, 4), 256, 0, stream>>>(PART, KSUM);

    // Q = x @ Wqkv[:,0:1024] + bqkv[0:1024]  (overwrites KV region; KV dead)
    gemm3_kernel<<<dim3(1024 / 256, ROWS / 256), 512, 0, stream>>>(
        xh, xl, Wqh, Wql, bqkv, KVQ, 1024, 1024);

    // context + normalization; writes ctx hi/lo over xh/xl (x dead)
    context_kernel<<<dim3(256, 16), 256, 0, stream>>>(
        KVQ, fcos, fsin, proj, KSUM, xh, xl);

    // out = ctx @ Wout + bout
    gemm3_kernel<<<dim3(1024 / 256, ROWS / 256), 512, 0, stream>>>(
        xh, xl, Woh, Wol, bout, out, 1024, 1024);
}